// Round 17
// baseline (3264.853 us; speedup 1.0000x reference)
//
#include <hip/hip_runtime.h>

// Problem constants
#define TSEQ 512
#define NB   32     // batch
#define DB   768    // d_bert
#define H2E  128    // encoder hidden per dir
#define DL   256    // d_lstm
#define NC   16     // n_class

typedef unsigned long long ull;
typedef float f32x4 __attribute__((ext_vector_type(4)));
typedef short bf16x8 __attribute__((ext_vector_type(8)));
typedef unsigned short u16x8 __attribute__((ext_vector_type(8)));

__device__ __forceinline__ float sigf(float x) { return 1.0f / (1.0f + __expf(-x)); }
__device__ __forceinline__ float tanhfast(float x) { return 1.0f - 2.0f / (1.0f + __expf(2.0f * x)); }

// split f32 -> hi bf16 (RNE) + lo bf16 (RNE of residual)
__device__ __forceinline__ void cvt_split(float a, unsigned short& hi, unsigned short& lo) {
    unsigned u = __float_as_uint(a);
    unsigned h = (u + 0x7FFFu + ((u >> 16) & 1u)) >> 16;
    float hf = __uint_as_float(h << 16);
    float d = a - hf;
    unsigned ud = __float_as_uint(d);
    unsigned l = (ud + 0x7FFFu + ((ud >> 16) & 1u)) >> 16;
    hi = (unsigned short)h;
    lo = (unsigned short)l;
}

// ---------------------------------------------------------------------------
// Split-bf16 MFMA GEMM (validated round 11).
// ---------------------------------------------------------------------------
#define LDST 40
template <int MODE>
__global__ __launch_bounds__(256) void gemm_mfma(
    const float* __restrict__ A, int lda,
    const float* __restrict__ W, int ldw,
    const float* __restrict__ b1, const float* __restrict__ b2,
    float* __restrict__ C, int ldc, int K)
{
    __shared__ unsigned short Ah[128][LDST];
    __shared__ unsigned short Al[128][LDST];
    __shared__ unsigned short Wh[128][LDST];
    __shared__ unsigned short Wl[128][LDST];

    const int tid = threadIdx.x;
    const int m0 = blockIdx.x * 128;
    const int n0 = blockIdx.y * 128;
    const int wave = tid >> 6, lane = tid & 63;
    const int wr = wave >> 1, wc = wave & 1;
    const int fr = lane & 15;
    const int fq = lane >> 4;
    const int srow = tid >> 1, skoff = (tid & 1) * 16;

    f32x4 acc[4][4] = {};

    for (int k0 = 0; k0 < K; k0 += 32) {
        __syncthreads();
        {
            const float* src = A + (size_t)(m0 + srow) * lda + k0 + skoff;
            u16x8 vh0, vh1, vl0, vl1;
#pragma unroll
            for (int e = 0; e < 8; ++e) {
                unsigned short h, l;
                cvt_split(src[e], h, l);
                vh0[e] = h; vl0[e] = l;
                cvt_split(src[e + 8], h, l);
                vh1[e] = h; vl1[e] = l;
            }
            *(u16x8*)&Ah[srow][skoff]     = vh0;
            *(u16x8*)&Ah[srow][skoff + 8] = vh1;
            *(u16x8*)&Al[srow][skoff]     = vl0;
            *(u16x8*)&Al[srow][skoff + 8] = vl1;
        }
        {
            const float* src = W + (size_t)(n0 + srow) * ldw + k0 + skoff;
            u16x8 vh0, vh1, vl0, vl1;
#pragma unroll
            for (int e = 0; e < 8; ++e) {
                unsigned short h, l;
                cvt_split(src[e], h, l);
                vh0[e] = h; vl0[e] = l;
                cvt_split(src[e + 8], h, l);
                vh1[e] = h; vl1[e] = l;
            }
            *(u16x8*)&Wh[srow][skoff]     = vh0;
            *(u16x8*)&Wh[srow][skoff + 8] = vh1;
            *(u16x8*)&Wl[srow][skoff]     = vl0;
            *(u16x8*)&Wl[srow][skoff + 8] = vl1;
        }
        __syncthreads();

        bf16x8 ah[4], al[4], bh[4], bl[4];
#pragma unroll
        for (int i = 0; i < 4; ++i) {
            const int r = wr * 64 + i * 16 + fr;
            ah[i] = *(const bf16x8*)&Ah[r][fq * 8];
            al[i] = *(const bf16x8*)&Al[r][fq * 8];
        }
#pragma unroll
        for (int j = 0; j < 4; ++j) {
            const int r = wc * 64 + j * 16 + fr;
            bh[j] = *(const bf16x8*)&Wh[r][fq * 8];
            bl[j] = *(const bf16x8*)&Wl[r][fq * 8];
        }
#pragma unroll
        for (int i = 0; i < 4; ++i)
#pragma unroll
            for (int j = 0; j < 4; ++j) {
                acc[i][j] = __builtin_amdgcn_mfma_f32_16x16x32_bf16(ah[i], bh[j], acc[i][j], 0, 0, 0);
                acc[i][j] = __builtin_amdgcn_mfma_f32_16x16x32_bf16(ah[i], bl[j], acc[i][j], 0, 0, 0);
                acc[i][j] = __builtin_amdgcn_mfma_f32_16x16x32_bf16(al[i], bh[j], acc[i][j], 0, 0, 0);
            }
    }

#pragma unroll
    for (int i = 0; i < 4; ++i) {
#pragma unroll
        for (int r = 0; r < 4; ++r) {
            int gm = m0 + wr * 64 + i * 16 + fq * 4 + r;
            int orow;
            if (MODE == 0) orow = gm;
            else {
                int bb = gm >> 9;
                int tt = gm & (TSEQ - 1);
                orow = (MODE == 1 ? tt : (TSEQ - 1 - tt)) * NB + bb;
            }
            float* crow = C + (size_t)orow * ldc;
#pragma unroll
            for (int j = 0; j < 4; ++j) {
                int gn = n0 + wc * 64 + j * 16 + fr;
                float bias = (b1 ? b1[gn] : 0.f) + (b2 ? b2[gn] : 0.f);
                crow[gn] = acc[i][j][r] + bias;
            }
        }
    }
}

// ---------------------------------------------------------------------------
// hs transpose+convert: hsT[b][d][j] (bf16 hi/lo planes) from hs cols 0:256.
// ---------------------------------------------------------------------------
__global__ __launch_bounds__(256) void hs_transpose(
    const float* __restrict__ hs,
    unsigned short* __restrict__ Th, unsigned short* __restrict__ Tl)
{
    __shared__ float T[64][65];
    const int tid = threadIdx.x;
    const int b  = blockIdx.z;
    const int j0 = blockIdx.x * 64;   // seq dim
    const int d0 = blockIdx.y * 64;   // feature dim
    const float* src = hs + ((size_t)b * TSEQ + j0) * 512 + d0;
#pragma unroll
    for (int it = 0; it < 4; ++it) {
        int jl = it * 16 + (tid >> 4);
        int dl = (tid & 15) * 4;
        float4 v = *(const float4*)(src + (size_t)jl * 512 + dl);
        T[jl][dl] = v.x; T[jl][dl + 1] = v.y; T[jl][dl + 2] = v.z; T[jl][dl + 3] = v.w;
    }
    __syncthreads();
#pragma unroll
    for (int it = 0; it < 4; ++it) {
        int dl = it * 16 + (tid >> 4);
        int jl = (tid & 15) * 4;
        ushort4 hi4, lo4;
        unsigned short h, l;
        cvt_split(T[jl][dl], h, l);     hi4.x = h; lo4.x = l;
        cvt_split(T[jl + 1][dl], h, l); hi4.y = h; lo4.y = l;
        cvt_split(T[jl + 2][dl], h, l); hi4.z = h; lo4.z = l;
        cvt_split(T[jl + 3][dl], h, l); hi4.w = h; lo4.w = l;
        size_t off = ((size_t)b * 256 + d0 + dl) * 512 + j0 + jl;
        *(ushort4*)(Th + off) = hi4;
        *(ushort4*)(Tl + off) = lo4;
    }
}

// ---------------------------------------------------------------------------
// Batched MFMA GEMM: ctx[b,i,d] = sum_j w[b,i,j] * hsT[b,d,j].
// ---------------------------------------------------------------------------
__global__ __launch_bounds__(256) void bgemm_mfma(
    const float* __restrict__ Wmat,
    const unsigned short* __restrict__ Th, const unsigned short* __restrict__ Tl,
    float* __restrict__ hs_ctx)
{
    __shared__ unsigned short Ah[128][LDST];
    __shared__ unsigned short Al[128][LDST];
    __shared__ unsigned short Bh[128][LDST];
    __shared__ unsigned short Bl[128][LDST];

    const int tid = threadIdx.x;
    const int b  = blockIdx.z;
    const int m0 = blockIdx.x * 128;
    const int n0 = blockIdx.y * 128;
    const int wave = tid >> 6, lane = tid & 63;
    const int wr = wave >> 1, wc = wave & 1;
    const int fr = lane & 15;
    const int fq = lane >> 4;
    const int srow = tid >> 1, skoff = (tid & 1) * 16;

    f32x4 acc[4][4] = {};

    for (int k0 = 0; k0 < TSEQ; k0 += 32) {
        __syncthreads();
        {
            const float* src = Wmat + (size_t)b * TSEQ * TSEQ
                             + (size_t)(m0 + srow) * TSEQ + k0 + skoff;
            u16x8 vh0, vh1, vl0, vl1;
#pragma unroll
            for (int e = 0; e < 8; ++e) {
                unsigned short h, l;
                cvt_split(src[e], h, l);
                vh0[e] = h; vl0[e] = l;
                cvt_split(src[e + 8], h, l);
                vh1[e] = h; vl1[e] = l;
            }
            *(u16x8*)&Ah[srow][skoff]     = vh0;
            *(u16x8*)&Ah[srow][skoff + 8] = vh1;
            *(u16x8*)&Al[srow][skoff]     = vl0;
            *(u16x8*)&Al[srow][skoff + 8] = vl1;
        }
        {
            size_t off = ((size_t)b * 256 + n0 + srow) * 512 + k0 + skoff;
            *(u16x8*)&Bh[srow][skoff]     = *(const u16x8*)(Th + off);
            *(u16x8*)&Bh[srow][skoff + 8] = *(const u16x8*)(Th + off + 8);
            *(u16x8*)&Bl[srow][skoff]     = *(const u16x8*)(Tl + off);
            *(u16x8*)&Bl[srow][skoff + 8] = *(const u16x8*)(Tl + off + 8);
        }
        __syncthreads();

        bf16x8 ah[4], al[4], bh[4], bl[4];
#pragma unroll
        for (int i = 0; i < 4; ++i) {
            const int r = wr * 64 + i * 16 + fr;
            ah[i] = *(const bf16x8*)&Ah[r][fq * 8];
            al[i] = *(const bf16x8*)&Al[r][fq * 8];
        }
#pragma unroll
        for (int j = 0; j < 4; ++j) {
            const int r = wc * 64 + j * 16 + fr;
            bh[j] = *(const bf16x8*)&Bh[r][fq * 8];
            bl[j] = *(const bf16x8*)&Bl[r][fq * 8];
        }
#pragma unroll
        for (int i = 0; i < 4; ++i)
#pragma unroll
            for (int j = 0; j < 4; ++j) {
                acc[i][j] = __builtin_amdgcn_mfma_f32_16x16x32_bf16(ah[i], bh[j], acc[i][j], 0, 0, 0);
                acc[i][j] = __builtin_amdgcn_mfma_f32_16x16x32_bf16(ah[i], bl[j], acc[i][j], 0, 0, 0);
                acc[i][j] = __builtin_amdgcn_mfma_f32_16x16x32_bf16(al[i], bh[j], acc[i][j], 0, 0, 0);
            }
    }

#pragma unroll
    for (int i = 0; i < 4; ++i) {
#pragma unroll
        for (int r = 0; r < 4; ++r) {
            int gm = m0 + wr * 64 + i * 16 + fq * 4 + r;
            float* crow = hs_ctx + ((size_t)b * TSEQ + gm) * 512 + 256;
#pragma unroll
            for (int j = 0; j < 4; ++j) {
                int gn = n0 + wc * 64 + j * 16 + fr;
                crow[gn] = acc[i][j][r];
            }
        }
    }
}

// ---------------------------------------------------------------------------
// f32 GEMM, 64x64 tile (tiny-N q/k projections only).
// ---------------------------------------------------------------------------
template <int MODE>
__global__ __launch_bounds__(256) void gemm_nt(
    const float* __restrict__ A, int lda,
    const float* __restrict__ W, int ldw,
    const float* __restrict__ b1, const float* __restrict__ b2,
    float* __restrict__ C, int ldc, int N, int K)
{
    __shared__ float As[16][68];
    __shared__ float Ws[16][68];
    const int tid = threadIdx.x;
    const int m0 = blockIdx.x * 64;
    const int n0 = blockIdx.y * 64;
    const int tx = tid & 15, ty = tid >> 4;
    const int lrow = tid >> 2;
    const int lk = (tid & 3) * 4;
    float acc[4][4] = {};

    for (int k0 = 0; k0 < K; k0 += 16) {
        float4 av = *(const float4*)(A + (size_t)(m0 + lrow) * lda + k0 + lk);
        float4 wv = make_float4(0.f, 0.f, 0.f, 0.f);
        if (n0 + lrow < N)
            wv = *(const float4*)(W + (size_t)(n0 + lrow) * ldw + k0 + lk);
        As[lk + 0][lrow] = av.x; As[lk + 1][lrow] = av.y;
        As[lk + 2][lrow] = av.z; As[lk + 3][lrow] = av.w;
        Ws[lk + 0][lrow] = wv.x; Ws[lk + 1][lrow] = wv.y;
        Ws[lk + 2][lrow] = wv.z; Ws[lk + 3][lrow] = wv.w;
        __syncthreads();
#pragma unroll
        for (int kk = 0; kk < 16; ++kk) {
            float a0 = As[kk][ty * 4 + 0], a1 = As[kk][ty * 4 + 1];
            float a2 = As[kk][ty * 4 + 2], a3 = As[kk][ty * 4 + 3];
            float w0 = Ws[kk][tx * 4 + 0], w1 = Ws[kk][tx * 4 + 1];
            float w2 = Ws[kk][tx * 4 + 2], w3 = Ws[kk][tx * 4 + 3];
            acc[0][0] += a0 * w0; acc[0][1] += a0 * w1; acc[0][2] += a0 * w2; acc[0][3] += a0 * w3;
            acc[1][0] += a1 * w0; acc[1][1] += a1 * w1; acc[1][2] += a1 * w2; acc[1][3] += a1 * w3;
            acc[2][0] += a2 * w0; acc[2][1] += a2 * w1; acc[2][2] += a2 * w2; acc[2][3] += a2 * w3;
            acc[3][0] += a3 * w0; acc[3][1] += a3 * w1; acc[3][2] += a3 * w2; acc[3][3] += a3 * w3;
        }
        __syncthreads();
    }

#pragma unroll
    for (int i = 0; i < 4; ++i) {
        int gm = m0 + ty * 4 + i;
        int orow;
        if (MODE == 0) orow = gm;
        else {
            int bb = gm >> 9;
            int tt = gm & (TSEQ - 1);
            orow = (MODE == 1 ? tt : (TSEQ - 1 - tt)) * NB + bb;
        }
#pragma unroll
        for (int j = 0; j < 4; ++j) {
            int gn = n0 + tx * 4 + j;
            if (gn < N) {
                float bias = (b1 ? b1[gn] : 0.f) + (b2 ? b2[gn] : 0.f);
                C[(size_t)orow * ldc + gn] = acc[i][j] + bias;
            }
        }
    }
}

// ---------------------------------------------------------------------------
// Encoder LSTM scan (validated LDS-broadcast version).
// ---------------------------------------------------------------------------
__global__ __launch_bounds__(512) void enc_scan(
    const float* __restrict__ Gf, const float* __restrict__ Gr,
    const float* __restrict__ Whh_f, const float* __restrict__ Whh_r,
    float* __restrict__ hs_ctx)
{
    const int dir = blockIdx.x & 1;
    const int b = blockIdx.x >> 1;
    const float* __restrict__ G = dir ? Gr : Gf;
    const float* __restrict__ Whh = dir ? Whh_r : Whh_f;
    const int j = threadIdx.x;

    __shared__ float4 h4[H2E / 4];
    __shared__ float gates[4 * H2E];
    float* h_s = (float*)h4;

    float4 w[32];
#pragma unroll
    for (int k = 0; k < 32; ++k)
        w[k] = *(const float4*)(Whh + (size_t)j * H2E + k * 4);

    float c = 0.f;
    if (j < H2E) h_s[j] = 0.f;
    __syncthreads();

    for (int t = 0; t < TSEQ; ++t) {
        const float* grow = G + ((size_t)t * NB + b) * 512;
        float acc = grow[j];
#pragma unroll
        for (int k = 0; k < 32; ++k) {
            float4 hv = h4[k];
            acc += w[k].x * hv.x + w[k].y * hv.y + w[k].z * hv.z + w[k].w * hv.w;
        }
        gates[j] = acc;
        __syncthreads();
        if (j < H2E) {
            float ig = sigf(gates[j]);
            float fg = sigf(gates[j + H2E]);
            float gg = tanhfast(gates[j + 2 * H2E]);
            float og = sigf(gates[j + 3 * H2E]);
            c = fg * c + ig * gg;
            float h = og * tanhfast(c);
            h_s[j] = h;
            int tout = dir ? (TSEQ - 1 - t) : t;
            hs_ctx[((size_t)b * TSEQ + tout) * 512 + dir * H2E + j] = h;
        }
        __syncthreads();
    }
}

// ---------------------------------------------------------------------------
// Fused additive-attention scores + softmax (unchanged).
// ---------------------------------------------------------------------------
__global__ __launch_bounds__(256) void attn_w(
    const float* __restrict__ qp, const float* __restrict__ kp,
    const int* __restrict__ mask, const float* __restrict__ fc2,
    float* __restrict__ wout)
{
    const int bi = blockIdx.x;
    const int b = bi >> 9;
    const int tid = threadIdx.x;
    __shared__ float kps[TSEQ * 11];
    __shared__ float red[8];

    const float* kpb = kp + (size_t)b * TSEQ * 10;
    for (int idx = tid; idx < TSEQ * 10; idx += 256) {
        int j = idx / 10, xx = idx - j * 10;
        kps[j * 11 + xx] = kpb[idx];
    }
    float q[10], vv[10];
#pragma unroll
    for (int xx = 0; xx < 10; ++xx) {
        q[xx] = qp[(size_t)bi * 10 + xx];
        vv[xx] = fc2[xx];
    }
    __syncthreads();

    float a[2];
#pragma unroll
    for (int jj = 0; jj < 2; ++jj) {
        int j = tid + jj * 256;
        float s = 0.f;
#pragma unroll
        for (int xx = 0; xx < 10; ++xx)
            s += vv[xx] * tanhfast(q[xx] + kps[j * 11 + xx]);
        if (mask[(size_t)b * TSEQ + j] == 0) s = -1e30f;
        a[jj] = s;
    }

    float m = fmaxf(a[0], a[1]);
#pragma unroll
    for (int o = 32; o >= 1; o >>= 1) m = fmaxf(m, __shfl_xor(m, o));
    if ((tid & 63) == 0) red[tid >> 6] = m;
    __syncthreads();
    m = fmaxf(fmaxf(red[0], red[1]), fmaxf(red[2], red[3]));

    float e0 = __expf(a[0] - m), e1 = __expf(a[1] - m);
    float s = e0 + e1;
#pragma unroll
    for (int o = 32; o >= 1; o >>= 1) s += __shfl_xor(s, o);
    if ((tid & 63) == 0) red[4 + (tid >> 6)] = s;
    __syncthreads();
    s = (red[4] + red[5]) + (red[6] + red[7]);
    float inv = 1.0f / s;
    wout[(size_t)bi * TSEQ + tid] = e0 * inv;
    wout[(size_t)bi * TSEQ + tid + 256] = e1 * inv;
}

// ---------------------------------------------------------------------------
// Decoder init v7: flags=1; hbuf parity 0 packed PAIRS of h(-1):
// word = (hi_e<<16|lo_e)<<32 | (hi_o<<16|lo_o) for units (2wp, 2wp+1).
// ---------------------------------------------------------------------------
__global__ __launch_bounds__(256) void dec_init7(
    const float* __restrict__ hs_ctx, ull* hbuf, int* flags)
{
    const int gid = blockIdx.x * 256 + threadIdx.x;
    if (gid < 128)
        __hip_atomic_store(flags + gid, 1, __ATOMIC_RELAXED, __HIP_MEMORY_SCOPE_AGENT);
    for (int idx = gid; idx < NB * 128; idx += 16 * 256) {
        int b = idx >> 7, wp = idx & 127;
        const float* hrow = hs_ctx + ((size_t)b * TSEQ + (TSEQ - 1)) * 512;
        unsigned short hh, hl;
        cvt_split(hrow[2 * wp], hh, hl);
        unsigned e32 = ((unsigned)hh << 16) | hl;
        cvt_split(hrow[2 * wp + 1], hh, hl);
        unsigned o32 = ((unsigned)hh << 16) | hl;
        __hip_atomic_store(hbuf + idx, ((ull)e32 << 32) | (ull)o32,
                           __ATOMIC_RELAXED, __HIP_MEMORY_SCOPE_AGENT);
    }
}

// ---------------------------------------------------------------------------
// Decoder scan v13: flag-after-drain sync (16 flag polls, not 1024 data
// polls) + pair-packed h words (512 bulk loads/block, single round).
// Publisher: 32 8B stores -> s_waitcnt vmcnt(0) -> 1 flag store (validated
// ordering recipe from scan3). Reader: 16 lanes poll 16 flags, barrier,
// one bulk load round, unpack to hi/lo LDS planes. MFMA dot + fused-logit
// wave4 tail unchanged from scan11.
// ---------------------------------------------------------------------------
__global__ __launch_bounds__(320) void dec_scan12(
    const float* __restrict__ Gd,     // (T, NB, 1024), biases folded
    const float* __restrict__ Whh,    // (1024, 256)
    const float* __restrict__ Wih,    // (1024, 272); cols 256:272 multiply y
    const float* __restrict__ lin_w,  // (16, 256)
    const float* __restrict__ lin_b,  // (16,)
    ull* hbuf,                        // (2, NB, 128) pair-packed h
    int* flags,                       // (128,)
    float* __restrict__ out)          // (NB, T, NC)
{
    const int tid = threadIdx.x;
    const int rg  = blockIdx.x & 15;
    const int bg  = blockIdx.x >> 4;
    const int wave = tid / 64;
    const int lane = tid & 63;
    const int fr = lane & 15;
    const int fq = lane >> 4;
    const bool isw4 = (wave == 4);
    const int ybb = (lane >> 4) & 3;
    const int ycls = lane & 15;

    __shared__ unsigned short wbh[64][264];
    __shared__ unsigned short wbl[64][264];
    __shared__ unsigned short lwh[16][264];
    __shared__ unsigned short lwl[16][264];
    __shared__ unsigned short hbh[4][264];
    __shared__ unsigned short hbl[4][264];
    __shared__ float gpart[4][4][18];
    __shared__ float lgp[4][18];
    __shared__ float wylds[64][17];

    for (int idx = tid; idx < 64 * 256; idx += 320) {
        int row = idx >> 8, c = idx & 255;
        int j = ((row >> 4) << 8) + rg * 16 + (row & 15);
        unsigned short h, l;
        cvt_split(Whh[(size_t)j * 256 + c], h, l);
        wbh[row][c] = h;
        wbl[row][c] = l;
    }
    for (int idx = tid; idx < 16 * 256; idx += 320) {
        int row = idx >> 8, c = idx & 255;
        unsigned short h, l;
        cvt_split(lin_w[(size_t)row * 256 + c], h, l);
        lwh[row][c] = h;
        lwl[row][c] = l;
    }
    for (int idx = tid; idx < 64 * 16; idx += 320) {
        int r = idx >> 4, c = idx & 15;
        int j = ((r >> 4) << 8) + rg * 16 + (r & 15);
        wylds[r][c] = Wih[(size_t)j * 272 + 256 + c];
    }
    const float lb = lin_b[ycls];
    float cstate = 0.f;
    __syncthreads();

    for (int t = 0; t <= TSEQ; ++t) {
        // Gd prefetch for wave4 finalize (independent of h)
        float gdv[4] = {0.f, 0.f, 0.f, 0.f};
        if (isw4 && t < TSEQ) {
            const float* gb = Gd + ((size_t)t * NB + bg * 4 + ybb) * 1024 + rg * 16 + ycls;
#pragma unroll
            for (int q = 0; q < 4; ++q) gdv[q] = gb[q * 256];
        }
        __builtin_amdgcn_sched_barrier(0);

        // ---- flag poll: 16 lanes watch the ring's 16 publishers ----
        if (tid < 16) {
            while (__hip_atomic_load(flags + bg * 16 + tid, __ATOMIC_RELAXED,
                                     __HIP_MEMORY_SCOPE_AGENT) < t + 1)
                __builtin_amdgcn_s_sleep(1);
        }
        __syncthreads();   // all publishers done; h(t-1) visible at L3

        // ---- bulk load: one round of 512 pair-words, unpack to LDS ----
        if (tid < 256) {
            const ull* hb = hbuf + (size_t)(t & 1) * (NB * 128) + (size_t)(bg * 4) * 128;
            const int bb = tid >> 6, wi = tid & 63;
            ull w0 = __hip_atomic_load(hb + bb * 128 + wi,      __ATOMIC_RELAXED, __HIP_MEMORY_SCOPE_AGENT);
            ull w1 = __hip_atomic_load(hb + bb * 128 + 64 + wi, __ATOMIC_RELAXED, __HIP_MEMORY_SCOPE_AGENT);
            *(unsigned*)&hbh[bb][2 * wi] =
                (unsigned)((w0 >> 48) & 0xFFFF) | ((unsigned)((w0 >> 16) & 0xFFFF) << 16);
            *(unsigned*)&hbl[bb][2 * wi] =
                (unsigned)((w0 >> 32) & 0xFFFF) | (((unsigned)w0 & 0xFFFF) << 16);
            *(unsigned*)&hbh[bb][128 + 2 * wi] =
                (unsigned)((w1 >> 48) & 0xFFFF) | ((unsigned)((w1 >> 16) & 0xFFFF) << 16);
            *(unsigned*)&hbl[bb][128 + 2 * wi] =
                (unsigned)((w1 >> 32) & 0xFFFF) | (((unsigned)w1 & 0xFFFF) << 16);
        }
        __syncthreads();   // hbh/hbl staged

        // ---- MFMA dot: 80 N-rows (64 gates + 16 logits), K=256 ----
        {
            f32x4 acc1 = {}, acc2 = {};
            const int abrow = lane & 3;
            const unsigned short* browh = isw4 ? &lwh[fr][0] : &wbh[wave * 16 + fr][0];
            const unsigned short* browl = isw4 ? &lwl[fr][0] : &wbl[wave * 16 + fr][0];
#pragma unroll
            for (int ks = 0; ks < 8; ++ks) {
                const int kc = ks * 32 + fq * 8;
                bf16x8 ahi = *(const bf16x8*)&hbh[abrow][kc];
                bf16x8 alo = *(const bf16x8*)&hbl[abrow][kc];
                bf16x8 bhi = *(const bf16x8*)&browh[kc];
                bf16x8 blo = *(const bf16x8*)&browl[kc];
                acc1 = __builtin_amdgcn_mfma_f32_16x16x32_bf16(ahi, bhi, acc1, 0, 0, 0);
                acc2 = __builtin_amdgcn_mfma_f32_16x16x32_bf16(ahi, blo, acc2, 0, 0, 0);
                acc2 = __builtin_amdgcn_mfma_f32_16x16x32_bf16(alo, bhi, acc2, 0, 0, 0);
            }
            if (fq == 0) {
#pragma unroll
                for (int reg = 0; reg < 4; ++reg) {
                    float v = acc1[reg] + acc2[reg];
                    if (isw4) lgp[reg][fr] = v;
                    else      gpart[wave][reg][fr] = v;
                }
            }
        }
        __syncthreads();   // gpart + lgp ready

        // ---- wave4 tail: softmax -> y, gates, LSTM, publish + flag ----
        if (isw4) {
            const int bb = ybb, u = ycls;
            float yv = 0.f;
            if (t > 0) {
                float lv = lgp[bb][u] + lb;
                float m = lv;
#pragma unroll
                for (int o = 1; o < 16; o <<= 1) m = fmaxf(m, __shfl_xor(m, o, 16));
                float e = __expf(lv - m);
                float ss = e;
#pragma unroll
                for (int o = 1; o < 16; o <<= 1) ss += __shfl_xor(ss, o, 16);
                yv = e / ss;
                if (rg == 0)
                    out[(((size_t)(bg * 4 + bb)) * TSEQ + (t - 1)) * NC + u] = yv;
            }
            if (t < TSEQ) {
                float g[4];
#pragma unroll
                for (int q = 0; q < 4; ++q) {
                    float s = gpart[q][bb][u] + gdv[q];
                    const int r = q * 16 + u;
#pragma unroll
                    for (int c = 0; c < 16; ++c) {
                        float yc = __shfl(yv, (lane & 48) | c);
                        s += wylds[r][c] * yc;
                    }
                    g[q] = s;
                }
                float ig = sigf(g[0]), fg = sigf(g[1]);
                float gv = tanhfast(g[2]), og = sigf(g[3]);
                cstate = fg * cstate + ig * gv;
                float h = og * tanhfast(cstate);
                unsigned short hh, hl;
                cvt_split(h, hh, hl);
                unsigned own32 = ((unsigned)hh << 16) | hl;
                unsigned partner32 = __shfl(own32, lane + 1);
                if ((u & 1) == 0) {
                    const ull word = ((ull)own32 << 32) | (ull)partner32;
                    const size_t oidx = (size_t)((t + 1) & 1) * (NB * 128)
                                      + (size_t)(bg * 4 + bb) * 128 + rg * 8 + (u >> 1);
                    __hip_atomic_store(hbuf + oidx, word,
                                       __ATOMIC_RELAXED, __HIP_MEMORY_SCOPE_AGENT);
                }
                // drain the wave's h-stores to the coherent point, then flag
                asm volatile("s_waitcnt vmcnt(0)" ::: "memory");
                if (lane == 0)
                    __hip_atomic_store(flags + blockIdx.x, t + 2,
                                       __ATOMIC_RELAXED, __HIP_MEMORY_SCOPE_AGENT);
            }
        }
        if (t == TSEQ) break;
    }
}

// ---------------------------------------------------------------------------
extern "C" void kernel_launch(void* const* d_in, const int* in_sizes, int n_in,
                              void* d_out, int out_size, void* d_ws, size_t ws_size,
                              hipStream_t stream)
{
    const float* x     = (const float*)d_in[0];
    const int*   mask  = (const int*)d_in[1];
    const float* Wih_f = (const float*)d_in[2];
    const float* Whh_f = (const float*)d_in[3];
    const float* bih_f = (const float*)d_in[4];
    const float* bhh_f = (const float*)d_in[5];
    const float* Wih_r = (const float*)d_in[6];
    const float* Whh_r = (const float*)d_in[7];
    const float* bih_r = (const float*)d_in[8];
    const float* bhh_r = (const float*)d_in[9];
    const float* fc1_w = (const float*)d_in[10];
    const float* fc2_w = (const float*)d_in[11];
    const float* fc3_w = (const float*)d_in[12];
    const float* fc3_b = (const float*)d_in[13];
    const float* Wih_d = (const float*)d_in[14];
    const float* Whh_d = (const float*)d_in[15];
    const float* bih_d = (const float*)d_in[16];
    const float* bhh_d = (const float*)d_in[17];
    const float* lin_w = (const float*)d_in[18];
    const float* lin_b = (const float*)d_in[19];

    float* ws = (float*)d_ws;
    float* Gf   = ws;
    float* Gr   = ws + 8388608;
    float* hs   = ws + 16777216;
    float* wat  = ws + 25165824;
    float* qp   = ws + 33554432;
    float* kp   = ws + 33718272;
    float* Gd   = ws;
    float* yenc = wat;
    ull* hbuf = (ull*)(wat + 4194304);        // 2*NB*128 = 8192 ull
    int* flags = (int*)(hbuf + 2 * NB * 128); // 128 ints after hbuf
    // hsT planes live in the Gf region (dead between enc_scan and Gd write)
    unsigned short* hsT_hi = (unsigned short*)ws;
    unsigned short* hsT_lo = (unsigned short*)(ws + 2097152);

    float* outp = (float*)d_out;
    const int M = NB * TSEQ;       // 16384
    dim3 blk(256);

    // 1-2. encoder input projections (split-bf16 MFMA, 128x128 tiles)
    gemm_mfma<1><<<dim3(M / 128, 4), blk, 0, stream>>>(x, DB, Wih_f, DB, bih_f, bhh_f, Gf, 512, DB);
    gemm_mfma<2><<<dim3(M / 128, 4), blk, 0, stream>>>(x, DB, Wih_r, DB, bih_r, bhh_r, Gr, 512, DB);
    // 3. bidirectional recurrence
    enc_scan<<<dim3(64), dim3(512), 0, stream>>>(Gf, Gr, Whh_f, Whh_r, hs);
    // 3.5 transpose hs cols 0:256 into bf16 planes (Gf region now dead)
    hs_transpose<<<dim3(8, 4, NB), blk, 0, stream>>>(hs, hsT_hi, hsT_lo);
    // 4-5. q/k projections (tiny N, f32 64x64)
    gemm_nt<0><<<dim3(M / 64, 1), blk, 0, stream>>>(hs, 512, fc1_w, 512, nullptr, nullptr, qp, 10, 10, 256);
    gemm_nt<0><<<dim3(M / 64, 1), blk, 0, stream>>>(hs, 512, fc1_w + 256, 512, nullptr, nullptr, kp, 10, 10, 256);
    // 6. attention scores + softmax
    attn_w<<<dim3(M), blk, 0, stream>>>(qp, kp, mask, fc2_w, wat);
    // 7. ctx = w @ hs (split-bf16 MFMA via transposed planes)
    bgemm_mfma<<<dim3(4, 2, NB), blk, 0, stream>>>(wat, hsT_hi, hsT_lo, hs);
    // 8. y_enc (split-bf16 MFMA)
    gemm_mfma<0><<<dim3(M / 128, 2), blk, 0, stream>>>(hs, 512, fc3_w, 512, fc3_b, nullptr, yenc, 256, 512);
    // 8.5 decoder comm init (pair-packed words + flags)
    dec_init7<<<dim3(16), blk, 0, stream>>>(hs, hbuf, flags);
    // 9. decoder input projection (split-bf16 MFMA)
    gemm_mfma<1><<<dim3(M / 128, 8), blk, 0, stream>>>(yenc, 256, Wih_d, 272, bih_d, bhh_d, Gd, 1024, 256);
    // 10. decoder recurrence (flag-after-drain sync, pair-packed publish)
    dec_scan12<<<dim3(128), dim3(320), 0, stream>>>(Gd, Whh_d, Wih_d, lin_w, lin_b, hbuf, flags, outp);
}

// Round 18
// 2595.610 us; speedup vs baseline: 1.2578x; 1.2578x over previous
//
#include <hip/hip_runtime.h>

// Problem constants
#define TSEQ 512
#define NB   32     // batch
#define DB   768    // d_bert
#define H2E  128    // encoder hidden per dir
#define DL   256    // d_lstm
#define NC   16     // n_class

typedef unsigned long long ull;
typedef float f32x4 __attribute__((ext_vector_type(4)));
typedef short bf16x8 __attribute__((ext_vector_type(8)));
typedef unsigned short u16x8 __attribute__((ext_vector_type(8)));

__device__ __forceinline__ float sigf(float x) { return 1.0f / (1.0f + __expf(-x)); }
__device__ __forceinline__ float tanhfast(float x) { return 1.0f - 2.0f / (1.0f + __expf(2.0f * x)); }

// split f32 -> hi bf16 (RNE) + lo bf16 (RNE of residual)
__device__ __forceinline__ void cvt_split(float a, unsigned short& hi, unsigned short& lo) {
    unsigned u = __float_as_uint(a);
    unsigned h = (u + 0x7FFFu + ((u >> 16) & 1u)) >> 16;
    float hf = __uint_as_float(h << 16);
    float d = a - hf;
    unsigned ud = __float_as_uint(d);
    unsigned l = (ud + 0x7FFFu + ((ud >> 16) & 1u)) >> 16;
    hi = (unsigned short)h;
    lo = (unsigned short)l;
}

// ---------------------------------------------------------------------------
// Split-bf16 MFMA GEMM (validated round 11).
// ---------------------------------------------------------------------------
#define LDST 40
template <int MODE>
__global__ __launch_bounds__(256) void gemm_mfma(
    const float* __restrict__ A, int lda,
    const float* __restrict__ W, int ldw,
    const float* __restrict__ b1, const float* __restrict__ b2,
    float* __restrict__ C, int ldc, int K)
{
    __shared__ unsigned short Ah[128][LDST];
    __shared__ unsigned short Al[128][LDST];
    __shared__ unsigned short Wh[128][LDST];
    __shared__ unsigned short Wl[128][LDST];

    const int tid = threadIdx.x;
    const int m0 = blockIdx.x * 128;
    const int n0 = blockIdx.y * 128;
    const int wave = tid >> 6, lane = tid & 63;
    const int wr = wave >> 1, wc = wave & 1;
    const int fr = lane & 15;
    const int fq = lane >> 4;
    const int srow = tid >> 1, skoff = (tid & 1) * 16;

    f32x4 acc[4][4] = {};

    for (int k0 = 0; k0 < K; k0 += 32) {
        __syncthreads();
        {
            const float* src = A + (size_t)(m0 + srow) * lda + k0 + skoff;
            u16x8 vh0, vh1, vl0, vl1;
#pragma unroll
            for (int e = 0; e < 8; ++e) {
                unsigned short h, l;
                cvt_split(src[e], h, l);
                vh0[e] = h; vl0[e] = l;
                cvt_split(src[e + 8], h, l);
                vh1[e] = h; vl1[e] = l;
            }
            *(u16x8*)&Ah[srow][skoff]     = vh0;
            *(u16x8*)&Ah[srow][skoff + 8] = vh1;
            *(u16x8*)&Al[srow][skoff]     = vl0;
            *(u16x8*)&Al[srow][skoff + 8] = vl1;
        }
        {
            const float* src = W + (size_t)(n0 + srow) * ldw + k0 + skoff;
            u16x8 vh0, vh1, vl0, vl1;
#pragma unroll
            for (int e = 0; e < 8; ++e) {
                unsigned short h, l;
                cvt_split(src[e], h, l);
                vh0[e] = h; vl0[e] = l;
                cvt_split(src[e + 8], h, l);
                vh1[e] = h; vl1[e] = l;
            }
            *(u16x8*)&Wh[srow][skoff]     = vh0;
            *(u16x8*)&Wh[srow][skoff + 8] = vh1;
            *(u16x8*)&Wl[srow][skoff]     = vl0;
            *(u16x8*)&Wl[srow][skoff + 8] = vl1;
        }
        __syncthreads();

        bf16x8 ah[4], al[4], bh[4], bl[4];
#pragma unroll
        for (int i = 0; i < 4; ++i) {
            const int r = wr * 64 + i * 16 + fr;
            ah[i] = *(const bf16x8*)&Ah[r][fq * 8];
            al[i] = *(const bf16x8*)&Al[r][fq * 8];
        }
#pragma unroll
        for (int j = 0; j < 4; ++j) {
            const int r = wc * 64 + j * 16 + fr;
            bh[j] = *(const bf16x8*)&Wh[r][fq * 8];
            bl[j] = *(const bf16x8*)&Wl[r][fq * 8];
        }
#pragma unroll
        for (int i = 0; i < 4; ++i)
#pragma unroll
            for (int j = 0; j < 4; ++j) {
                acc[i][j] = __builtin_amdgcn_mfma_f32_16x16x32_bf16(ah[i], bh[j], acc[i][j], 0, 0, 0);
                acc[i][j] = __builtin_amdgcn_mfma_f32_16x16x32_bf16(ah[i], bl[j], acc[i][j], 0, 0, 0);
                acc[i][j] = __builtin_amdgcn_mfma_f32_16x16x32_bf16(al[i], bh[j], acc[i][j], 0, 0, 0);
            }
    }

#pragma unroll
    for (int i = 0; i < 4; ++i) {
#pragma unroll
        for (int r = 0; r < 4; ++r) {
            int gm = m0 + wr * 64 + i * 16 + fq * 4 + r;
            int orow;
            if (MODE == 0) orow = gm;
            else {
                int bb = gm >> 9;
                int tt = gm & (TSEQ - 1);
                orow = (MODE == 1 ? tt : (TSEQ - 1 - tt)) * NB + bb;
            }
            float* crow = C + (size_t)orow * ldc;
#pragma unroll
            for (int j = 0; j < 4; ++j) {
                int gn = n0 + wc * 64 + j * 16 + fr;
                float bias = (b1 ? b1[gn] : 0.f) + (b2 ? b2[gn] : 0.f);
                crow[gn] = acc[i][j][r] + bias;
            }
        }
    }
}

// ---------------------------------------------------------------------------
// hs transpose+convert: hsT[b][d][j] (bf16 hi/lo planes) from hs cols 0:256.
// ---------------------------------------------------------------------------
__global__ __launch_bounds__(256) void hs_transpose(
    const float* __restrict__ hs,
    unsigned short* __restrict__ Th, unsigned short* __restrict__ Tl)
{
    __shared__ float T[64][65];
    const int tid = threadIdx.x;
    const int b  = blockIdx.z;
    const int j0 = blockIdx.x * 64;   // seq dim
    const int d0 = blockIdx.y * 64;   // feature dim
    const float* src = hs + ((size_t)b * TSEQ + j0) * 512 + d0;
#pragma unroll
    for (int it = 0; it < 4; ++it) {
        int jl = it * 16 + (tid >> 4);
        int dl = (tid & 15) * 4;
        float4 v = *(const float4*)(src + (size_t)jl * 512 + dl);
        T[jl][dl] = v.x; T[jl][dl + 1] = v.y; T[jl][dl + 2] = v.z; T[jl][dl + 3] = v.w;
    }
    __syncthreads();
#pragma unroll
    for (int it = 0; it < 4; ++it) {
        int dl = it * 16 + (tid >> 4);
        int jl = (tid & 15) * 4;
        ushort4 hi4, lo4;
        unsigned short h, l;
        cvt_split(T[jl][dl], h, l);     hi4.x = h; lo4.x = l;
        cvt_split(T[jl + 1][dl], h, l); hi4.y = h; lo4.y = l;
        cvt_split(T[jl + 2][dl], h, l); hi4.z = h; lo4.z = l;
        cvt_split(T[jl + 3][dl], h, l); hi4.w = h; lo4.w = l;
        size_t off = ((size_t)b * 256 + d0 + dl) * 512 + j0 + jl;
        *(ushort4*)(Th + off) = hi4;
        *(ushort4*)(Tl + off) = lo4;
    }
}

// ---------------------------------------------------------------------------
// Batched MFMA GEMM: ctx[b,i,d] = sum_j w[b,i,j] * hsT[b,d,j].
// ---------------------------------------------------------------------------
__global__ __launch_bounds__(256) void bgemm_mfma(
    const float* __restrict__ Wmat,
    const unsigned short* __restrict__ Th, const unsigned short* __restrict__ Tl,
    float* __restrict__ hs_ctx)
{
    __shared__ unsigned short Ah[128][LDST];
    __shared__ unsigned short Al[128][LDST];
    __shared__ unsigned short Bh[128][LDST];
    __shared__ unsigned short Bl[128][LDST];

    const int tid = threadIdx.x;
    const int b  = blockIdx.z;
    const int m0 = blockIdx.x * 128;
    const int n0 = blockIdx.y * 128;
    const int wave = tid >> 6, lane = tid & 63;
    const int wr = wave >> 1, wc = wave & 1;
    const int fr = lane & 15;
    const int fq = lane >> 4;
    const int srow = tid >> 1, skoff = (tid & 1) * 16;

    f32x4 acc[4][4] = {};

    for (int k0 = 0; k0 < TSEQ; k0 += 32) {
        __syncthreads();
        {
            const float* src = Wmat + (size_t)b * TSEQ * TSEQ
                             + (size_t)(m0 + srow) * TSEQ + k0 + skoff;
            u16x8 vh0, vh1, vl0, vl1;
#pragma unroll
            for (int e = 0; e < 8; ++e) {
                unsigned short h, l;
                cvt_split(src[e], h, l);
                vh0[e] = h; vl0[e] = l;
                cvt_split(src[e + 8], h, l);
                vh1[e] = h; vl1[e] = l;
            }
            *(u16x8*)&Ah[srow][skoff]     = vh0;
            *(u16x8*)&Ah[srow][skoff + 8] = vh1;
            *(u16x8*)&Al[srow][skoff]     = vl0;
            *(u16x8*)&Al[srow][skoff + 8] = vl1;
        }
        {
            size_t off = ((size_t)b * 256 + n0 + srow) * 512 + k0 + skoff;
            *(u16x8*)&Bh[srow][skoff]     = *(const u16x8*)(Th + off);
            *(u16x8*)&Bh[srow][skoff + 8] = *(const u16x8*)(Th + off + 8);
            *(u16x8*)&Bl[srow][skoff]     = *(const u16x8*)(Tl + off);
            *(u16x8*)&Bl[srow][skoff + 8] = *(const u16x8*)(Tl + off + 8);
        }
        __syncthreads();

        bf16x8 ah[4], al[4], bh[4], bl[4];
#pragma unroll
        for (int i = 0; i < 4; ++i) {
            const int r = wr * 64 + i * 16 + fr;
            ah[i] = *(const bf16x8*)&Ah[r][fq * 8];
            al[i] = *(const bf16x8*)&Al[r][fq * 8];
        }
#pragma unroll
        for (int j = 0; j < 4; ++j) {
            const int r = wc * 64 + j * 16 + fr;
            bh[j] = *(const bf16x8*)&Bh[r][fq * 8];
            bl[j] = *(const bf16x8*)&Bl[r][fq * 8];
        }
#pragma unroll
        for (int i = 0; i < 4; ++i)
#pragma unroll
            for (int j = 0; j < 4; ++j) {
                acc[i][j] = __builtin_amdgcn_mfma_f32_16x16x32_bf16(ah[i], bh[j], acc[i][j], 0, 0, 0);
                acc[i][j] = __builtin_amdgcn_mfma_f32_16x16x32_bf16(ah[i], bl[j], acc[i][j], 0, 0, 0);
                acc[i][j] = __builtin_amdgcn_mfma_f32_16x16x32_bf16(al[i], bh[j], acc[i][j], 0, 0, 0);
            }
    }

#pragma unroll
    for (int i = 0; i < 4; ++i) {
#pragma unroll
        for (int r = 0; r < 4; ++r) {
            int gm = m0 + wr * 64 + i * 16 + fq * 4 + r;
            float* crow = hs_ctx + ((size_t)b * TSEQ + gm) * 512 + 256;
#pragma unroll
            for (int j = 0; j < 4; ++j) {
                int gn = n0 + wc * 64 + j * 16 + fr;
                crow[gn] = acc[i][j][r];
            }
        }
    }
}

// ---------------------------------------------------------------------------
// f32 GEMM, 64x64 tile (tiny-N q/k projections only).
// ---------------------------------------------------------------------------
template <int MODE>
__global__ __launch_bounds__(256) void gemm_nt(
    const float* __restrict__ A, int lda,
    const float* __restrict__ W, int ldw,
    const float* __restrict__ b1, const float* __restrict__ b2,
    float* __restrict__ C, int ldc, int N, int K)
{
    __shared__ float As[16][68];
    __shared__ float Ws[16][68];
    const int tid = threadIdx.x;
    const int m0 = blockIdx.x * 64;
    const int n0 = blockIdx.y * 64;
    const int tx = tid & 15, ty = tid >> 4;
    const int lrow = tid >> 2;
    const int lk = (tid & 3) * 4;
    float acc[4][4] = {};

    for (int k0 = 0; k0 < K; k0 += 16) {
        float4 av = *(const float4*)(A + (size_t)(m0 + lrow) * lda + k0 + lk);
        float4 wv = make_float4(0.f, 0.f, 0.f, 0.f);
        if (n0 + lrow < N)
            wv = *(const float4*)(W + (size_t)(n0 + lrow) * ldw + k0 + lk);
        As[lk + 0][lrow] = av.x; As[lk + 1][lrow] = av.y;
        As[lk + 2][lrow] = av.z; As[lk + 3][lrow] = av.w;
        Ws[lk + 0][lrow] = wv.x; Ws[lk + 1][lrow] = wv.y;
        Ws[lk + 2][lrow] = wv.z; Ws[lk + 3][lrow] = wv.w;
        __syncthreads();
#pragma unroll
        for (int kk = 0; kk < 16; ++kk) {
            float a0 = As[kk][ty * 4 + 0], a1 = As[kk][ty * 4 + 1];
            float a2 = As[kk][ty * 4 + 2], a3 = As[kk][ty * 4 + 3];
            float w0 = Ws[kk][tx * 4 + 0], w1 = Ws[kk][tx * 4 + 1];
            float w2 = Ws[kk][tx * 4 + 2], w3 = Ws[kk][tx * 4 + 3];
            acc[0][0] += a0 * w0; acc[0][1] += a0 * w1; acc[0][2] += a0 * w2; acc[0][3] += a0 * w3;
            acc[1][0] += a1 * w0; acc[1][1] += a1 * w1; acc[1][2] += a1 * w2; acc[1][3] += a1 * w3;
            acc[2][0] += a2 * w0; acc[2][1] += a2 * w1; acc[2][2] += a2 * w2; acc[2][3] += a2 * w3;
            acc[3][0] += a3 * w0; acc[3][1] += a3 * w1; acc[3][2] += a3 * w2; acc[3][3] += a3 * w3;
        }
        __syncthreads();
    }

#pragma unroll
    for (int i = 0; i < 4; ++i) {
        int gm = m0 + ty * 4 + i;
        int orow;
        if (MODE == 0) orow = gm;
        else {
            int bb = gm >> 9;
            int tt = gm & (TSEQ - 1);
            orow = (MODE == 1 ? tt : (TSEQ - 1 - tt)) * NB + bb;
        }
#pragma unroll
        for (int j = 0; j < 4; ++j) {
            int gn = n0 + tx * 4 + j;
            if (gn < N) {
                float bias = (b1 ? b1[gn] : 0.f) + (b2 ? b2[gn] : 0.f);
                C[(size_t)orow * ldc + gn] = acc[i][j] + bias;
            }
        }
    }
}

// ---------------------------------------------------------------------------
// Encoder LSTM scan (validated LDS-broadcast version).
// ---------------------------------------------------------------------------
__global__ __launch_bounds__(512) void enc_scan(
    const float* __restrict__ Gf, const float* __restrict__ Gr,
    const float* __restrict__ Whh_f, const float* __restrict__ Whh_r,
    float* __restrict__ hs_ctx)
{
    const int dir = blockIdx.x & 1;
    const int b = blockIdx.x >> 1;
    const float* __restrict__ G = dir ? Gr : Gf;
    const float* __restrict__ Whh = dir ? Whh_r : Whh_f;
    const int j = threadIdx.x;

    __shared__ float4 h4[H2E / 4];
    __shared__ float gates[4 * H2E];
    float* h_s = (float*)h4;

    float4 w[32];
#pragma unroll
    for (int k = 0; k < 32; ++k)
        w[k] = *(const float4*)(Whh + (size_t)j * H2E + k * 4);

    float c = 0.f;
    if (j < H2E) h_s[j] = 0.f;
    __syncthreads();

    for (int t = 0; t < TSEQ; ++t) {
        const float* grow = G + ((size_t)t * NB + b) * 512;
        float acc = grow[j];
#pragma unroll
        for (int k = 0; k < 32; ++k) {
            float4 hv = h4[k];
            acc += w[k].x * hv.x + w[k].y * hv.y + w[k].z * hv.z + w[k].w * hv.w;
        }
        gates[j] = acc;
        __syncthreads();
        if (j < H2E) {
            float ig = sigf(gates[j]);
            float fg = sigf(gates[j + H2E]);
            float gg = tanhfast(gates[j + 2 * H2E]);
            float og = sigf(gates[j + 3 * H2E]);
            c = fg * c + ig * gg;
            float h = og * tanhfast(c);
            h_s[j] = h;
            int tout = dir ? (TSEQ - 1 - t) : t;
            hs_ctx[((size_t)b * TSEQ + tout) * 512 + dir * H2E + j] = h;
        }
        __syncthreads();
    }
}

// ---------------------------------------------------------------------------
// Fused additive-attention scores + softmax (unchanged).
// ---------------------------------------------------------------------------
__global__ __launch_bounds__(256) void attn_w(
    const float* __restrict__ qp, const float* __restrict__ kp,
    const int* __restrict__ mask, const float* __restrict__ fc2,
    float* __restrict__ wout)
{
    const int bi = blockIdx.x;
    const int b = bi >> 9;
    const int tid = threadIdx.x;
    __shared__ float kps[TSEQ * 11];
    __shared__ float red[8];

    const float* kpb = kp + (size_t)b * TSEQ * 10;
    for (int idx = tid; idx < TSEQ * 10; idx += 256) {
        int j = idx / 10, xx = idx - j * 10;
        kps[j * 11 + xx] = kpb[idx];
    }
    float q[10], vv[10];
#pragma unroll
    for (int xx = 0; xx < 10; ++xx) {
        q[xx] = qp[(size_t)bi * 10 + xx];
        vv[xx] = fc2[xx];
    }
    __syncthreads();

    float a[2];
#pragma unroll
    for (int jj = 0; jj < 2; ++jj) {
        int j = tid + jj * 256;
        float s = 0.f;
#pragma unroll
        for (int xx = 0; xx < 10; ++xx)
            s += vv[xx] * tanhfast(q[xx] + kps[j * 11 + xx]);
        if (mask[(size_t)b * TSEQ + j] == 0) s = -1e30f;
        a[jj] = s;
    }

    float m = fmaxf(a[0], a[1]);
#pragma unroll
    for (int o = 32; o >= 1; o >>= 1) m = fmaxf(m, __shfl_xor(m, o));
    if ((tid & 63) == 0) red[tid >> 6] = m;
    __syncthreads();
    m = fmaxf(fmaxf(red[0], red[1]), fmaxf(red[2], red[3]));

    float e0 = __expf(a[0] - m), e1 = __expf(a[1] - m);
    float s = e0 + e1;
#pragma unroll
    for (int o = 32; o >= 1; o >>= 1) s += __shfl_xor(s, o);
    if ((tid & 63) == 0) red[4 + (tid >> 6)] = s;
    __syncthreads();
    s = (red[4] + red[5]) + (red[6] + red[7]);
    float inv = 1.0f / s;
    wout[(size_t)bi * TSEQ + tid] = e0 * inv;
    wout[(size_t)bi * TSEQ + tid + 256] = e1 * inv;
}

// ---------------------------------------------------------------------------
// Decoder init: clear hbuf tags (both parities); seed h(-1) PRE-SPLIT
// (word = tag<<32 | hi<<16 | lo) into parity 0, tag=1.
// ---------------------------------------------------------------------------
__global__ __launch_bounds__(256) void dec_init6(
    const float* __restrict__ hs_ctx, ull* hbuf)
{
    const int gid = blockIdx.x * 256 + threadIdx.x;
    for (int idx = gid; idx < 16384; idx += 16 * 256) {
        ull v = 0ull;
        if (idx < 8192) {
            int b = idx >> 8, u = idx & 255;
            float hv = hs_ctx[((size_t)b * TSEQ + (TSEQ - 1)) * 512 + u];
            unsigned short hh, hl;
            cvt_split(hv, hh, hl);
            v = (1ull << 32) | ((ull)hh << 16) | (ull)hl;
        }
        __hip_atomic_store(hbuf + idx, v, __ATOMIC_RELAXED, __HIP_MEMORY_SCOPE_AGENT);
    }
}

// ---------------------------------------------------------------------------
// Decoder scan v14 = scan11 (validated single-hop data-tag sync) with the
// poll restructured to LOCKSTEP: wave0's 64 lanes poll all 1024 tagged
// words (16 coalesced loads/lane/round), wave-uniform __all() detect --
// removes the per-thread straggler round (~900cy/step) that scan11's
// unsynchronized 256-thread polling paid at the stage barrier.
// Publish side identical to scan11 (per-unit tag|hi|lo words, no drain).
// ---------------------------------------------------------------------------
__global__ __launch_bounds__(320) void dec_scan13(
    const float* __restrict__ Gd,     // (T, NB, 1024), biases folded
    const float* __restrict__ Whh,    // (1024, 256)
    const float* __restrict__ Wih,    // (1024, 272); cols 256:272 multiply y
    const float* __restrict__ lin_w,  // (16, 256)
    const float* __restrict__ lin_b,  // (16,)
    ull* hbuf,                        // (2, NB, 256) tagged packed h
    float* __restrict__ out)          // (NB, T, NC)
{
    const int tid = threadIdx.x;
    const int rg  = blockIdx.x & 15;
    const int bg  = blockIdx.x >> 4;
    const int wave = tid / 64;
    const int lane = tid & 63;
    const int fr = lane & 15;
    const int fq = lane >> 4;
    const bool isw4 = (wave == 4);
    const int ybb = (lane >> 4) & 3;
    const int ycls = lane & 15;

    __shared__ unsigned short wbh[64][264];
    __shared__ unsigned short wbl[64][264];
    __shared__ unsigned short lwh[16][264];
    __shared__ unsigned short lwl[16][264];
    __shared__ unsigned short hbh[4][264];
    __shared__ unsigned short hbl[4][264];
    __shared__ float gpart[4][4][18];
    __shared__ float lgp[4][18];
    __shared__ float wylds[64][17];

    for (int idx = tid; idx < 64 * 256; idx += 320) {
        int row = idx >> 8, c = idx & 255;
        int j = ((row >> 4) << 8) + rg * 16 + (row & 15);
        unsigned short h, l;
        cvt_split(Whh[(size_t)j * 256 + c], h, l);
        wbh[row][c] = h;
        wbl[row][c] = l;
    }
    for (int idx = tid; idx < 16 * 256; idx += 320) {
        int row = idx >> 8, c = idx & 255;
        unsigned short h, l;
        cvt_split(lin_w[(size_t)row * 256 + c], h, l);
        lwh[row][c] = h;
        lwl[row][c] = l;
    }
    for (int idx = tid; idx < 64 * 16; idx += 320) {
        int r = idx >> 4, c = idx & 15;
        int j = ((r >> 4) << 8) + rg * 16 + (r & 15);
        wylds[r][c] = Wih[(size_t)j * 272 + 256 + c];
    }
    const float lb = lin_b[ycls];
    float cstate = 0.f;
    __syncthreads();

    for (int t = 0; t <= TSEQ; ++t) {
        const unsigned want = (unsigned)(t + 1);
        const ull* hsrc = hbuf + (size_t)(t & 1) * 8192 + (size_t)bg * 1024;

        // Gd prefetch for wave4 finalize (independent of h)
        float gdv[4] = {0.f, 0.f, 0.f, 0.f};
        if (isw4 && t < TSEQ) {
            const float* gb = Gd + ((size_t)t * NB + bg * 4 + ybb) * 1024 + rg * 16 + ycls;
#pragma unroll
            for (int q = 0; q < 4; ++q) gdv[q] = gb[q * 256];
        }
        __builtin_amdgcn_sched_barrier(0);

        // ---- wave0: lockstep poll of all 1024 tagged words, stage to LDS ----
        if (wave == 0) {
            ull w[16];
            for (;;) {
                bool ok = true;
#pragma unroll
                for (int r = 0; r < 16; ++r) {
                    w[r] = __hip_atomic_load(hsrc + r * 64 + lane,
                                             __ATOMIC_RELAXED, __HIP_MEMORY_SCOPE_AGENT);
                    ok &= ((unsigned)(w[r] >> 32) == want);
                }
                if (__all(ok)) break;   // wave-uniform detect
                __builtin_amdgcn_s_sleep(1);
            }
#pragma unroll
            for (int r = 0; r < 16; ++r) {
                const int widx = r * 64 + lane;
                const int bb = widx >> 8, unit = widx & 255;
                hbh[bb][unit] = (unsigned short)(w[r] >> 16);
                hbl[bb][unit] = (unsigned short)w[r];
            }
        }
        __syncthreads();   // hbh/hbl staged

        // ---- MFMA dot: 80 N-rows (64 gates + 16 logits), K=256 ----
        {
            f32x4 acc1 = {}, acc2 = {};
            const int abrow = lane & 3;
            const unsigned short* browh = isw4 ? &lwh[fr][0] : &wbh[wave * 16 + fr][0];
            const unsigned short* browl = isw4 ? &lwl[fr][0] : &wbl[wave * 16 + fr][0];
#pragma unroll
            for (int ks = 0; ks < 8; ++ks) {
                const int kc = ks * 32 + fq * 8;
                bf16x8 ahi = *(const bf16x8*)&hbh[abrow][kc];
                bf16x8 alo = *(const bf16x8*)&hbl[abrow][kc];
                bf16x8 bhi = *(const bf16x8*)&browh[kc];
                bf16x8 blo = *(const bf16x8*)&browl[kc];
                acc1 = __builtin_amdgcn_mfma_f32_16x16x32_bf16(ahi, bhi, acc1, 0, 0, 0);
                acc2 = __builtin_amdgcn_mfma_f32_16x16x32_bf16(ahi, blo, acc2, 0, 0, 0);
                acc2 = __builtin_amdgcn_mfma_f32_16x16x32_bf16(alo, bhi, acc2, 0, 0, 0);
            }
            if (fq == 0) {
#pragma unroll
                for (int reg = 0; reg < 4; ++reg) {
                    float v = acc1[reg] + acc2[reg];
                    if (isw4) lgp[reg][fr] = v;
                    else      gpart[wave][reg][fr] = v;
                }
            }
        }
        __syncthreads();   // gpart + lgp ready

        // ---- wave4 tail: softmax -> y, gates, LSTM, publish packed h ----
        if (isw4) {
            const int bb = ybb, u = ycls;
            float yv = 0.f;
            if (t > 0) {
                float lv = lgp[bb][u] + lb;
                float m = lv;
#pragma unroll
                for (int o = 1; o < 16; o <<= 1) m = fmaxf(m, __shfl_xor(m, o, 16));
                float e = __expf(lv - m);
                float ss = e;
#pragma unroll
                for (int o = 1; o < 16; o <<= 1) ss += __shfl_xor(ss, o, 16);
                yv = e / ss;
                if (rg == 0)
                    out[(((size_t)(bg * 4 + bb)) * TSEQ + (t - 1)) * NC + u] = yv;
            }
            if (t < TSEQ) {
                float g[4];
#pragma unroll
                for (int q = 0; q < 4; ++q) {
                    float s = gpart[q][bb][u] + gdv[q];
                    const int r = q * 16 + u;
#pragma unroll
                    for (int c = 0; c < 16; ++c) {
                        float yc = __shfl(yv, (lane & 48) | c);
                        s += wylds[r][c] * yc;
                    }
                    g[q] = s;
                }
                float ig = sigf(g[0]), fg = sigf(g[1]);
                float gv = tanhfast(g[2]), og = sigf(g[3]);
                cstate = fg * cstate + ig * gv;
                float h = og * tanhfast(cstate);
                unsigned short hh, hl;
                cvt_split(h, hh, hl);
                const ull word = (((ull)(unsigned)(t + 2)) << 32)
                               | ((ull)hh << 16) | (ull)hl;
                const size_t oidx = (size_t)((t + 1) & 1) * 8192
                                  + (size_t)(bg * 4 + bb) * 256 + rg * 16 + u;
                __hip_atomic_store(hbuf + oidx, word,
                                   __ATOMIC_RELAXED, __HIP_MEMORY_SCOPE_AGENT);
            }
        }
        if (t == TSEQ) break;
        // no trailing barrier: next-step poll self-gates on wave4's publish,
        // and hbh/gpart rewrites are ordered behind the stage/dot barriers.
    }
}

// ---------------------------------------------------------------------------
extern "C" void kernel_launch(void* const* d_in, const int* in_sizes, int n_in,
                              void* d_out, int out_size, void* d_ws, size_t ws_size,
                              hipStream_t stream)
{
    const float* x     = (const float*)d_in[0];
    const int*   mask  = (const int*)d_in[1];
    const float* Wih_f = (const float*)d_in[2];
    const float* Whh_f = (const float*)d_in[3];
    const float* bih_f = (const float*)d_in[4];
    const float* bhh_f = (const float*)d_in[5];
    const float* Wih_r = (const float*)d_in[6];
    const float* Whh_r = (const float*)d_in[7];
    const float* bih_r = (const float*)d_in[8];
    const float* bhh_r = (const float*)d_in[9];
    const float* fc1_w = (const float*)d_in[10];
    const float* fc2_w = (const float*)d_in[11];
    const float* fc3_w = (const float*)d_in[12];
    const float* fc3_b = (const float*)d_in[13];
    const float* Wih_d = (const float*)d_in[14];
    const float* Whh_d = (const float*)d_in[15];
    const float* bih_d = (const float*)d_in[16];
    const float* bhh_d = (const float*)d_in[17];
    const float* lin_w = (const float*)d_in[18];
    const float* lin_b = (const float*)d_in[19];

    float* ws = (float*)d_ws;
    float* Gf   = ws;
    float* Gr   = ws + 8388608;
    float* hs   = ws + 16777216;
    float* wat  = ws + 25165824;
    float* qp   = ws + 33554432;
    float* kp   = ws + 33718272;
    float* Gd   = ws;
    float* yenc = wat;
    ull* hbuf = (ull*)(wat + 4194304);   // 2*NB*256 tagged words
    // hsT planes live in the Gf region (dead between enc_scan and Gd write)
    unsigned short* hsT_hi = (unsigned short*)ws;
    unsigned short* hsT_lo = (unsigned short*)(ws + 2097152);

    float* outp = (float*)d_out;
    const int M = NB * TSEQ;       // 16384
    dim3 blk(256);

    // 1-2. encoder input projections (split-bf16 MFMA, 128x128 tiles)
    gemm_mfma<1><<<dim3(M / 128, 4), blk, 0, stream>>>(x, DB, Wih_f, DB, bih_f, bhh_f, Gf, 512, DB);
    gemm_mfma<2><<<dim3(M / 128, 4), blk, 0, stream>>>(x, DB, Wih_r, DB, bih_r, bhh_r, Gr, 512, DB);
    // 3. bidirectional recurrence
    enc_scan<<<dim3(64), dim3(512), 0, stream>>>(Gf, Gr, Whh_f, Whh_r, hs);
    // 3.5 transpose hs cols 0:256 into bf16 planes (Gf region now dead)
    hs_transpose<<<dim3(8, 4, NB), blk, 0, stream>>>(hs, hsT_hi, hsT_lo);
    // 4-5. q/k projections (tiny N, f32 64x64)
    gemm_nt<0><<<dim3(M / 64, 1), blk, 0, stream>>>(hs, 512, fc1_w, 512, nullptr, nullptr, qp, 10, 10, 256);
    gemm_nt<0><<<dim3(M / 64, 1), blk, 0, stream>>>(hs, 512, fc1_w + 256, 512, nullptr, nullptr, kp, 10, 10, 256);
    // 6. attention scores + softmax
    attn_w<<<dim3(M), blk, 0, stream>>>(qp, kp, mask, fc2_w, wat);
    // 7. ctx = w @ hs (split-bf16 MFMA via transposed planes)
    bgemm_mfma<<<dim3(4, 2, NB), blk, 0, stream>>>(wat, hsT_hi, hsT_lo, hs);
    // 8. y_enc (split-bf16 MFMA)
    gemm_mfma<0><<<dim3(M / 128, 2), blk, 0, stream>>>(hs, 512, fc3_w, 512, fc3_b, nullptr, yenc, 256, 512);
    // 8.5 decoder comm init (pre-split packed words)
    dec_init6<<<dim3(16), blk, 0, stream>>>(hs, hbuf);
    // 9. decoder input projection (split-bf16 MFMA)
    gemm_mfma<1><<<dim3(M / 128, 8), blk, 0, stream>>>(yenc, 256, Wih_d, 272, bih_d, bhh_d, Gd, 1024, 256);
    // 10. decoder recurrence (lockstep wave0 poll, single-hop tag sync)
    dec_scan13<<<dim3(128), dim3(320), 0, stream>>>(Gd, Whh_d, Wih_d, lin_w, lin_b, hbuf, outp);
}

// Round 19
// 2281.023 us; speedup vs baseline: 1.4313x; 1.1379x over previous
//
#include <hip/hip_runtime.h>

// Problem constants
#define TSEQ 512
#define NB   32     // batch
#define DB   768    // d_bert
#define H2E  128    // encoder hidden per dir
#define DL   256    // d_lstm
#define NC   16     // n_class

typedef unsigned long long ull;
typedef float f32x4 __attribute__((ext_vector_type(4)));
typedef short bf16x8 __attribute__((ext_vector_type(8)));
typedef unsigned short u16x8 __attribute__((ext_vector_type(8)));

__device__ __forceinline__ float sigf(float x) { return 1.0f / (1.0f + __expf(-x)); }
__device__ __forceinline__ float tanhfast(float x) { return 1.0f - 2.0f / (1.0f + __expf(2.0f * x)); }

// split f32 -> hi bf16 (RNE) + lo bf16 (RNE of residual)
__device__ __forceinline__ void cvt_split(float a, unsigned short& hi, unsigned short& lo) {
    unsigned u = __float_as_uint(a);
    unsigned h = (u + 0x7FFFu + ((u >> 16) & 1u)) >> 16;
    float hf = __uint_as_float(h << 16);
    float d = a - hf;
    unsigned ud = __float_as_uint(d);
    unsigned l = (ud + 0x7FFFu + ((ud >> 16) & 1u)) >> 16;
    hi = (unsigned short)h;
    lo = (unsigned short)l;
}

// ---------------------------------------------------------------------------
// Split-bf16 MFMA GEMM (validated round 11).
// ---------------------------------------------------------------------------
#define LDST 40
template <int MODE>
__global__ __launch_bounds__(256) void gemm_mfma(
    const float* __restrict__ A, int lda,
    const float* __restrict__ W, int ldw,
    const float* __restrict__ b1, const float* __restrict__ b2,
    float* __restrict__ C, int ldc, int K)
{
    __shared__ unsigned short Ah[128][LDST];
    __shared__ unsigned short Al[128][LDST];
    __shared__ unsigned short Wh[128][LDST];
    __shared__ unsigned short Wl[128][LDST];

    const int tid = threadIdx.x;
    const int m0 = blockIdx.x * 128;
    const int n0 = blockIdx.y * 128;
    const int wave = tid >> 6, lane = tid & 63;
    const int wr = wave >> 1, wc = wave & 1;
    const int fr = lane & 15;
    const int fq = lane >> 4;
    const int srow = tid >> 1, skoff = (tid & 1) * 16;

    f32x4 acc[4][4] = {};

    for (int k0 = 0; k0 < K; k0 += 32) {
        __syncthreads();
        {
            const float* src = A + (size_t)(m0 + srow) * lda + k0 + skoff;
            u16x8 vh0, vh1, vl0, vl1;
#pragma unroll
            for (int e = 0; e < 8; ++e) {
                unsigned short h, l;
                cvt_split(src[e], h, l);
                vh0[e] = h; vl0[e] = l;
                cvt_split(src[e + 8], h, l);
                vh1[e] = h; vl1[e] = l;
            }
            *(u16x8*)&Ah[srow][skoff]     = vh0;
            *(u16x8*)&Ah[srow][skoff + 8] = vh1;
            *(u16x8*)&Al[srow][skoff]     = vl0;
            *(u16x8*)&Al[srow][skoff + 8] = vl1;
        }
        {
            const float* src = W + (size_t)(n0 + srow) * ldw + k0 + skoff;
            u16x8 vh0, vh1, vl0, vl1;
#pragma unroll
            for (int e = 0; e < 8; ++e) {
                unsigned short h, l;
                cvt_split(src[e], h, l);
                vh0[e] = h; vl0[e] = l;
                cvt_split(src[e + 8], h, l);
                vh1[e] = h; vl1[e] = l;
            }
            *(u16x8*)&Wh[srow][skoff]     = vh0;
            *(u16x8*)&Wh[srow][skoff + 8] = vh1;
            *(u16x8*)&Wl[srow][skoff]     = vl0;
            *(u16x8*)&Wl[srow][skoff + 8] = vl1;
        }
        __syncthreads();

        bf16x8 ah[4], al[4], bh[4], bl[4];
#pragma unroll
        for (int i = 0; i < 4; ++i) {
            const int r = wr * 64 + i * 16 + fr;
            ah[i] = *(const bf16x8*)&Ah[r][fq * 8];
            al[i] = *(const bf16x8*)&Al[r][fq * 8];
        }
#pragma unroll
        for (int j = 0; j < 4; ++j) {
            const int r = wc * 64 + j * 16 + fr;
            bh[j] = *(const bf16x8*)&Wh[r][fq * 8];
            bl[j] = *(const bf16x8*)&Wl[r][fq * 8];
        }
#pragma unroll
        for (int i = 0; i < 4; ++i)
#pragma unroll
            for (int j = 0; j < 4; ++j) {
                acc[i][j] = __builtin_amdgcn_mfma_f32_16x16x32_bf16(ah[i], bh[j], acc[i][j], 0, 0, 0);
                acc[i][j] = __builtin_amdgcn_mfma_f32_16x16x32_bf16(ah[i], bl[j], acc[i][j], 0, 0, 0);
                acc[i][j] = __builtin_amdgcn_mfma_f32_16x16x32_bf16(al[i], bh[j], acc[i][j], 0, 0, 0);
            }
    }

#pragma unroll
    for (int i = 0; i < 4; ++i) {
#pragma unroll
        for (int r = 0; r < 4; ++r) {
            int gm = m0 + wr * 64 + i * 16 + fq * 4 + r;
            int orow;
            if (MODE == 0) orow = gm;
            else {
                int bb = gm >> 9;
                int tt = gm & (TSEQ - 1);
                orow = (MODE == 1 ? tt : (TSEQ - 1 - tt)) * NB + bb;
            }
            float* crow = C + (size_t)orow * ldc;
#pragma unroll
            for (int j = 0; j < 4; ++j) {
                int gn = n0 + wc * 64 + j * 16 + fr;
                float bias = (b1 ? b1[gn] : 0.f) + (b2 ? b2[gn] : 0.f);
                crow[gn] = acc[i][j][r] + bias;
            }
        }
    }
}

// ---------------------------------------------------------------------------
// hs transpose+convert: hsT[b][d][j] (bf16 hi/lo planes) from hs cols 0:256.
// ---------------------------------------------------------------------------
__global__ __launch_bounds__(256) void hs_transpose(
    const float* __restrict__ hs,
    unsigned short* __restrict__ Th, unsigned short* __restrict__ Tl)
{
    __shared__ float T[64][65];
    const int tid = threadIdx.x;
    const int b  = blockIdx.z;
    const int j0 = blockIdx.x * 64;   // seq dim
    const int d0 = blockIdx.y * 64;   // feature dim
    const float* src = hs + ((size_t)b * TSEQ + j0) * 512 + d0;
#pragma unroll
    for (int it = 0; it < 4; ++it) {
        int jl = it * 16 + (tid >> 4);
        int dl = (tid & 15) * 4;
        float4 v = *(const float4*)(src + (size_t)jl * 512 + dl);
        T[jl][dl] = v.x; T[jl][dl + 1] = v.y; T[jl][dl + 2] = v.z; T[jl][dl + 3] = v.w;
    }
    __syncthreads();
#pragma unroll
    for (int it = 0; it < 4; ++it) {
        int dl = it * 16 + (tid >> 4);
        int jl = (tid & 15) * 4;
        ushort4 hi4, lo4;
        unsigned short h, l;
        cvt_split(T[jl][dl], h, l);     hi4.x = h; lo4.x = l;
        cvt_split(T[jl + 1][dl], h, l); hi4.y = h; lo4.y = l;
        cvt_split(T[jl + 2][dl], h, l); hi4.z = h; lo4.z = l;
        cvt_split(T[jl + 3][dl], h, l); hi4.w = h; lo4.w = l;
        size_t off = ((size_t)b * 256 + d0 + dl) * 512 + j0 + jl;
        *(ushort4*)(Th + off) = hi4;
        *(ushort4*)(Tl + off) = lo4;
    }
}

// ---------------------------------------------------------------------------
// Batched MFMA GEMM: ctx[b,i,d] = sum_j w[b,i,j] * hsT[b,d,j].
// ---------------------------------------------------------------------------
__global__ __launch_bounds__(256) void bgemm_mfma(
    const float* __restrict__ Wmat,
    const unsigned short* __restrict__ Th, const unsigned short* __restrict__ Tl,
    float* __restrict__ hs_ctx)
{
    __shared__ unsigned short Ah[128][LDST];
    __shared__ unsigned short Al[128][LDST];
    __shared__ unsigned short Bh[128][LDST];
    __shared__ unsigned short Bl[128][LDST];

    const int tid = threadIdx.x;
    const int b  = blockIdx.z;
    const int m0 = blockIdx.x * 128;
    const int n0 = blockIdx.y * 128;
    const int wave = tid >> 6, lane = tid & 63;
    const int wr = wave >> 1, wc = wave & 1;
    const int fr = lane & 15;
    const int fq = lane >> 4;
    const int srow = tid >> 1, skoff = (tid & 1) * 16;

    f32x4 acc[4][4] = {};

    for (int k0 = 0; k0 < TSEQ; k0 += 32) {
        __syncthreads();
        {
            const float* src = Wmat + (size_t)b * TSEQ * TSEQ
                             + (size_t)(m0 + srow) * TSEQ + k0 + skoff;
            u16x8 vh0, vh1, vl0, vl1;
#pragma unroll
            for (int e = 0; e < 8; ++e) {
                unsigned short h, l;
                cvt_split(src[e], h, l);
                vh0[e] = h; vl0[e] = l;
                cvt_split(src[e + 8], h, l);
                vh1[e] = h; vl1[e] = l;
            }
            *(u16x8*)&Ah[srow][skoff]     = vh0;
            *(u16x8*)&Ah[srow][skoff + 8] = vh1;
            *(u16x8*)&Al[srow][skoff]     = vl0;
            *(u16x8*)&Al[srow][skoff + 8] = vl1;
        }
        {
            size_t off = ((size_t)b * 256 + n0 + srow) * 512 + k0 + skoff;
            *(u16x8*)&Bh[srow][skoff]     = *(const u16x8*)(Th + off);
            *(u16x8*)&Bh[srow][skoff + 8] = *(const u16x8*)(Th + off + 8);
            *(u16x8*)&Bl[srow][skoff]     = *(const u16x8*)(Tl + off);
            *(u16x8*)&Bl[srow][skoff + 8] = *(const u16x8*)(Tl + off + 8);
        }
        __syncthreads();

        bf16x8 ah[4], al[4], bh[4], bl[4];
#pragma unroll
        for (int i = 0; i < 4; ++i) {
            const int r = wr * 64 + i * 16 + fr;
            ah[i] = *(const bf16x8*)&Ah[r][fq * 8];
            al[i] = *(const bf16x8*)&Al[r][fq * 8];
        }
#pragma unroll
        for (int j = 0; j < 4; ++j) {
            const int r = wc * 64 + j * 16 + fr;
            bh[j] = *(const bf16x8*)&Bh[r][fq * 8];
            bl[j] = *(const bf16x8*)&Bl[r][fq * 8];
        }
#pragma unroll
        for (int i = 0; i < 4; ++i)
#pragma unroll
            for (int j = 0; j < 4; ++j) {
                acc[i][j] = __builtin_amdgcn_mfma_f32_16x16x32_bf16(ah[i], bh[j], acc[i][j], 0, 0, 0);
                acc[i][j] = __builtin_amdgcn_mfma_f32_16x16x32_bf16(ah[i], bl[j], acc[i][j], 0, 0, 0);
                acc[i][j] = __builtin_amdgcn_mfma_f32_16x16x32_bf16(al[i], bh[j], acc[i][j], 0, 0, 0);
            }
    }

#pragma unroll
    for (int i = 0; i < 4; ++i) {
#pragma unroll
        for (int r = 0; r < 4; ++r) {
            int gm = m0 + wr * 64 + i * 16 + fq * 4 + r;
            float* crow = hs_ctx + ((size_t)b * TSEQ + gm) * 512 + 256;
#pragma unroll
            for (int j = 0; j < 4; ++j) {
                int gn = n0 + wc * 64 + j * 16 + fr;
                crow[gn] = acc[i][j][r];
            }
        }
    }
}

// ---------------------------------------------------------------------------
// f32 GEMM, 64x64 tile (tiny-N q/k projections only).
// ---------------------------------------------------------------------------
template <int MODE>
__global__ __launch_bounds__(256) void gemm_nt(
    const float* __restrict__ A, int lda,
    const float* __restrict__ W, int ldw,
    const float* __restrict__ b1, const float* __restrict__ b2,
    float* __restrict__ C, int ldc, int N, int K)
{
    __shared__ float As[16][68];
    __shared__ float Ws[16][68];
    const int tid = threadIdx.x;
    const int m0 = blockIdx.x * 64;
    const int n0 = blockIdx.y * 64;
    const int tx = tid & 15, ty = tid >> 4;
    const int lrow = tid >> 2;
    const int lk = (tid & 3) * 4;
    float acc[4][4] = {};

    for (int k0 = 0; k0 < K; k0 += 16) {
        float4 av = *(const float4*)(A + (size_t)(m0 + lrow) * lda + k0 + lk);
        float4 wv = make_float4(0.f, 0.f, 0.f, 0.f);
        if (n0 + lrow < N)
            wv = *(const float4*)(W + (size_t)(n0 + lrow) * ldw + k0 + lk);
        As[lk + 0][lrow] = av.x; As[lk + 1][lrow] = av.y;
        As[lk + 2][lrow] = av.z; As[lk + 3][lrow] = av.w;
        Ws[lk + 0][lrow] = wv.x; Ws[lk + 1][lrow] = wv.y;
        Ws[lk + 2][lrow] = wv.z; Ws[lk + 3][lrow] = wv.w;
        __syncthreads();
#pragma unroll
        for (int kk = 0; kk < 16; ++kk) {
            float a0 = As[kk][ty * 4 + 0], a1 = As[kk][ty * 4 + 1];
            float a2 = As[kk][ty * 4 + 2], a3 = As[kk][ty * 4 + 3];
            float w0 = Ws[kk][tx * 4 + 0], w1 = Ws[kk][tx * 4 + 1];
            float w2 = Ws[kk][tx * 4 + 2], w3 = Ws[kk][tx * 4 + 3];
            acc[0][0] += a0 * w0; acc[0][1] += a0 * w1; acc[0][2] += a0 * w2; acc[0][3] += a0 * w3;
            acc[1][0] += a1 * w0; acc[1][1] += a1 * w1; acc[1][2] += a1 * w2; acc[1][3] += a1 * w3;
            acc[2][0] += a2 * w0; acc[2][1] += a2 * w1; acc[2][2] += a2 * w2; acc[2][3] += a2 * w3;
            acc[3][0] += a3 * w0; acc[3][1] += a3 * w1; acc[3][2] += a3 * w2; acc[3][3] += a3 * w3;
        }
        __syncthreads();
    }

#pragma unroll
    for (int i = 0; i < 4; ++i) {
        int gm = m0 + ty * 4 + i;
        int orow;
        if (MODE == 0) orow = gm;
        else {
            int bb = gm >> 9;
            int tt = gm & (TSEQ - 1);
            orow = (MODE == 1 ? tt : (TSEQ - 1 - tt)) * NB + bb;
        }
#pragma unroll
        for (int j = 0; j < 4; ++j) {
            int gn = n0 + tx * 4 + j;
            if (gn < N) {
                float bias = (b1 ? b1[gn] : 0.f) + (b2 ? b2[gn] : 0.f);
                C[(size_t)orow * ldc + gn] = acc[i][j] + bias;
            }
        }
    }
}

// ---------------------------------------------------------------------------
// Encoder LSTM scan (validated LDS-broadcast version).
// ---------------------------------------------------------------------------
__global__ __launch_bounds__(512) void enc_scan(
    const float* __restrict__ Gf, const float* __restrict__ Gr,
    const float* __restrict__ Whh_f, const float* __restrict__ Whh_r,
    float* __restrict__ hs_ctx)
{
    const int dir = blockIdx.x & 1;
    const int b = blockIdx.x >> 1;
    const float* __restrict__ G = dir ? Gr : Gf;
    const float* __restrict__ Whh = dir ? Whh_r : Whh_f;
    const int j = threadIdx.x;

    __shared__ float4 h4[H2E / 4];
    __shared__ float gates[4 * H2E];
    float* h_s = (float*)h4;

    float4 w[32];
#pragma unroll
    for (int k = 0; k < 32; ++k)
        w[k] = *(const float4*)(Whh + (size_t)j * H2E + k * 4);

    float c = 0.f;
    if (j < H2E) h_s[j] = 0.f;
    __syncthreads();

    for (int t = 0; t < TSEQ; ++t) {
        const float* grow = G + ((size_t)t * NB + b) * 512;
        float acc = grow[j];
#pragma unroll
        for (int k = 0; k < 32; ++k) {
            float4 hv = h4[k];
            acc += w[k].x * hv.x + w[k].y * hv.y + w[k].z * hv.z + w[k].w * hv.w;
        }
        gates[j] = acc;
        __syncthreads();
        if (j < H2E) {
            float ig = sigf(gates[j]);
            float fg = sigf(gates[j + H2E]);
            float gg = tanhfast(gates[j + 2 * H2E]);
            float og = sigf(gates[j + 3 * H2E]);
            c = fg * c + ig * gg;
            float h = og * tanhfast(c);
            h_s[j] = h;
            int tout = dir ? (TSEQ - 1 - t) : t;
            hs_ctx[((size_t)b * TSEQ + tout) * 512 + dir * H2E + j] = h;
        }
        __syncthreads();
    }
}

// ---------------------------------------------------------------------------
// Fused additive-attention scores + softmax (unchanged).
// ---------------------------------------------------------------------------
__global__ __launch_bounds__(256) void attn_w(
    const float* __restrict__ qp, const float* __restrict__ kp,
    const int* __restrict__ mask, const float* __restrict__ fc2,
    float* __restrict__ wout)
{
    const int bi = blockIdx.x;
    const int b = bi >> 9;
    const int tid = threadIdx.x;
    __shared__ float kps[TSEQ * 11];
    __shared__ float red[8];

    const float* kpb = kp + (size_t)b * TSEQ * 10;
    for (int idx = tid; idx < TSEQ * 10; idx += 256) {
        int j = idx / 10, xx = idx - j * 10;
        kps[j * 11 + xx] = kpb[idx];
    }
    float q[10], vv[10];
#pragma unroll
    for (int xx = 0; xx < 10; ++xx) {
        q[xx] = qp[(size_t)bi * 10 + xx];
        vv[xx] = fc2[xx];
    }
    __syncthreads();

    float a[2];
#pragma unroll
    for (int jj = 0; jj < 2; ++jj) {
        int j = tid + jj * 256;
        float s = 0.f;
#pragma unroll
        for (int xx = 0; xx < 10; ++xx)
            s += vv[xx] * tanhfast(q[xx] + kps[j * 11 + xx]);
        if (mask[(size_t)b * TSEQ + j] == 0) s = -1e30f;
        a[jj] = s;
    }

    float m = fmaxf(a[0], a[1]);
#pragma unroll
    for (int o = 32; o >= 1; o >>= 1) m = fmaxf(m, __shfl_xor(m, o));
    if ((tid & 63) == 0) red[tid >> 6] = m;
    __syncthreads();
    m = fmaxf(fmaxf(red[0], red[1]), fmaxf(red[2], red[3]));

    float e0 = __expf(a[0] - m), e1 = __expf(a[1] - m);
    float s = e0 + e1;
#pragma unroll
    for (int o = 32; o >= 1; o >>= 1) s += __shfl_xor(s, o);
    if ((tid & 63) == 0) red[4 + (tid >> 6)] = s;
    __syncthreads();
    s = (red[4] + red[5]) + (red[6] + red[7]);
    float inv = 1.0f / s;
    wout[(size_t)bi * TSEQ + tid] = e0 * inv;
    wout[(size_t)bi * TSEQ + tid + 256] = e1 * inv;
}

// ---------------------------------------------------------------------------
// Decoder init: clear hbuf tags (both parities); seed h(-1) PRE-SPLIT
// (word = tag<<32 | hi<<16 | lo) into parity 0, tag=1.
// ---------------------------------------------------------------------------
__global__ __launch_bounds__(256) void dec_init6(
    const float* __restrict__ hs_ctx, ull* hbuf)
{
    const int gid = blockIdx.x * 256 + threadIdx.x;
    for (int idx = gid; idx < 16384; idx += 16 * 256) {
        ull v = 0ull;
        if (idx < 8192) {
            int b = idx >> 8, u = idx & 255;
            float hv = hs_ctx[((size_t)b * TSEQ + (TSEQ - 1)) * 512 + u];
            unsigned short hh, hl;
            cvt_split(hv, hh, hl);
            v = (1ull << 32) | ((ull)hh << 16) | (ull)hl;
        }
        __hip_atomic_store(hbuf + idx, v, __ATOMIC_RELAXED, __HIP_MEMORY_SCOPE_AGENT);
    }
}

// ---------------------------------------------------------------------------
// Decoder scan v15 = scan11 (best-known: distributed data-tag single-hop
// sync, pre-split packed publish) + WEIGHT FRAGMENTS HOISTED TO VGPRs:
// each lane's 16 B-operand bf16x8 fragments (8 K-steps x hi/lo) are loaded
// from LDS once before the t-loop (they are step-invariant), halving the
// per-step LDS b128 issue (32 -> 16 reads/lane). VGPR budget: 88+64 = ~152,
// fine at 5 waves/block. Verification: VGPR_Count should read ~140-160.
// ---------------------------------------------------------------------------
__global__ __launch_bounds__(320) void dec_scan14(
    const float* __restrict__ Gd,     // (T, NB, 1024), biases folded
    const float* __restrict__ Whh,    // (1024, 256)
    const float* __restrict__ Wih,    // (1024, 272); cols 256:272 multiply y
    const float* __restrict__ lin_w,  // (16, 256)
    const float* __restrict__ lin_b,  // (16,)
    ull* hbuf,                        // (2, NB, 256) tagged packed h
    float* __restrict__ out)          // (NB, T, NC)
{
    const int tid = threadIdx.x;
    const int rg  = blockIdx.x & 15;
    const int bg  = blockIdx.x >> 4;
    const int wave = tid / 64;
    const int lane = tid & 63;
    const int fr = lane & 15;
    const int fq = lane >> 4;
    const bool isw4 = (wave == 4);
    const int ybb = (lane >> 4) & 3;
    const int ycls = lane & 15;

    __shared__ unsigned short wbh[64][264];
    __shared__ unsigned short wbl[64][264];
    __shared__ unsigned short lwh[16][264];
    __shared__ unsigned short lwl[16][264];
    __shared__ unsigned short hbh[4][264];
    __shared__ unsigned short hbl[4][264];
    __shared__ float gpart[4][4][18];
    __shared__ float lgp[4][18];
    __shared__ float wylds[64][17];

    for (int idx = tid; idx < 64 * 256; idx += 320) {
        int row = idx >> 8, c = idx & 255;
        int j = ((row >> 4) << 8) + rg * 16 + (row & 15);
        unsigned short h, l;
        cvt_split(Whh[(size_t)j * 256 + c], h, l);
        wbh[row][c] = h;
        wbl[row][c] = l;
    }
    for (int idx = tid; idx < 16 * 256; idx += 320) {
        int row = idx >> 8, c = idx & 255;
        unsigned short h, l;
        cvt_split(lin_w[(size_t)row * 256 + c], h, l);
        lwh[row][c] = h;
        lwl[row][c] = l;
    }
    for (int idx = tid; idx < 64 * 16; idx += 320) {
        int r = idx >> 4, c = idx & 15;
        int j = ((r >> 4) << 8) + rg * 16 + (r & 15);
        wylds[r][c] = Wih[(size_t)j * 272 + 256 + c];
    }
    const float lb = lin_b[ycls];
    float cstate = 0.f;
    __syncthreads();

    // ---- hoist step-invariant weight fragments into VGPRs ----
    bf16x8 wfh[8], wfl[8];
    {
        const unsigned short* browh = isw4 ? &lwh[fr][0] : &wbh[wave * 16 + fr][0];
        const unsigned short* browl = isw4 ? &lwl[fr][0] : &wbl[wave * 16 + fr][0];
#pragma unroll
        for (int ks = 0; ks < 8; ++ks) {
            wfh[ks] = *(const bf16x8*)&browh[ks * 32 + fq * 8];
            wfl[ks] = *(const bf16x8*)&browl[ks * 32 + fq * 8];
        }
    }

    for (int t = 0; t <= TSEQ; ++t) {
        const unsigned want = (unsigned)(t + 1);
        const ull* hsrc = hbuf + (size_t)(t & 1) * 8192 + (size_t)bg * 1024;

        // Gd prefetch for wave4 finalize (independent of h)
        float gdv[4] = {0.f, 0.f, 0.f, 0.f};
        if (isw4 && t < TSEQ) {
            const float* gb = Gd + ((size_t)t * NB + bg * 4 + ybb) * 1024 + rg * 16 + ycls;
#pragma unroll
            for (int q = 0; q < 4; ++q) gdv[q] = gb[q * 256];
        }
        __builtin_amdgcn_sched_barrier(0);

        // ---- threads 0-255: verify own 4 packed h-words; unpack + stage ----
        if (tid < 256) {
            ull h0, h1, h2, h3;
            for (;;) {
                h0 = __hip_atomic_load(hsrc + tid,       __ATOMIC_RELAXED, __HIP_MEMORY_SCOPE_AGENT);
                h1 = __hip_atomic_load(hsrc + tid + 256, __ATOMIC_RELAXED, __HIP_MEMORY_SCOPE_AGENT);
                h2 = __hip_atomic_load(hsrc + tid + 512, __ATOMIC_RELAXED, __HIP_MEMORY_SCOPE_AGENT);
                h3 = __hip_atomic_load(hsrc + tid + 768, __ATOMIC_RELAXED, __HIP_MEMORY_SCOPE_AGENT);
                if (((unsigned)(h0 >> 32) == want) && ((unsigned)(h1 >> 32) == want) &&
                    ((unsigned)(h2 >> 32) == want) && ((unsigned)(h3 >> 32) == want))
                    break;
                __builtin_amdgcn_s_sleep(1);
            }
            hbh[0][tid] = (unsigned short)(h0 >> 16); hbl[0][tid] = (unsigned short)h0;
            hbh[1][tid] = (unsigned short)(h1 >> 16); hbl[1][tid] = (unsigned short)h1;
            hbh[2][tid] = (unsigned short)(h2 >> 16); hbl[2][tid] = (unsigned short)h2;
            hbh[3][tid] = (unsigned short)(h3 >> 16); hbl[3][tid] = (unsigned short)h3;
        }
        __syncthreads();

        // ---- MFMA dot: 80 N-rows (64 gates + 16 logits), K=256 ----
        {
            f32x4 acc1 = {}, acc2 = {};
            const int abrow = lane & 3;
#pragma unroll
            for (int ks = 0; ks < 8; ++ks) {
                const int kc = ks * 32 + fq * 8;
                bf16x8 ahi = *(const bf16x8*)&hbh[abrow][kc];
                bf16x8 alo = *(const bf16x8*)&hbl[abrow][kc];
                acc1 = __builtin_amdgcn_mfma_f32_16x16x32_bf16(ahi, wfh[ks], acc1, 0, 0, 0);
                acc2 = __builtin_amdgcn_mfma_f32_16x16x32_bf16(ahi, wfl[ks], acc2, 0, 0, 0);
                acc2 = __builtin_amdgcn_mfma_f32_16x16x32_bf16(alo, wfh[ks], acc2, 0, 0, 0);
            }
            if (fq == 0) {
#pragma unroll
                for (int reg = 0; reg < 4; ++reg) {
                    float v = acc1[reg] + acc2[reg];
                    if (isw4) lgp[reg][fr] = v;
                    else      gpart[wave][reg][fr] = v;
                }
            }
        }
        __syncthreads();

        // ---- wave4 tail: softmax -> y, gates, LSTM, publish packed h ----
        if (isw4) {
            const int bb = ybb, u = ycls;
            float yv = 0.f;
            if (t > 0) {
                float lv = lgp[bb][u] + lb;
                float m = lv;
#pragma unroll
                for (int o = 1; o < 16; o <<= 1) m = fmaxf(m, __shfl_xor(m, o, 16));
                float e = __expf(lv - m);
                float ss = e;
#pragma unroll
                for (int o = 1; o < 16; o <<= 1) ss += __shfl_xor(ss, o, 16);
                yv = e / ss;
                if (rg == 0)
                    out[(((size_t)(bg * 4 + bb)) * TSEQ + (t - 1)) * NC + u] = yv;
            }
            if (t < TSEQ) {
                float g[4];
#pragma unroll
                for (int q = 0; q < 4; ++q) {
                    float s = gpart[q][bb][u] + gdv[q];
                    const int r = q * 16 + u;
#pragma unroll
                    for (int c = 0; c < 16; ++c) {
                        float yc = __shfl(yv, (lane & 48) | c);
                        s += wylds[r][c] * yc;
                    }
                    g[q] = s;
                }
                float ig = sigf(g[0]), fg = sigf(g[1]);
                float gv = tanhfast(g[2]), og = sigf(g[3]);
                cstate = fg * cstate + ig * gv;
                float h = og * tanhfast(cstate);
                unsigned short hh, hl;
                cvt_split(h, hh, hl);
                const ull word = (((ull)(unsigned)(t + 2)) << 32)
                               | ((ull)hh << 16) | (ull)hl;
                const size_t oidx = (size_t)((t + 1) & 1) * 8192
                                  + (size_t)(bg * 4 + bb) * 256 + rg * 16 + u;
                __hip_atomic_store(hbuf + oidx, word,
                                   __ATOMIC_RELAXED, __HIP_MEMORY_SCOPE_AGENT);
            }
        }
        if (t == TSEQ) break;
    }
}

// ---------------------------------------------------------------------------
extern "C" void kernel_launch(void* const* d_in, const int* in_sizes, int n_in,
                              void* d_out, int out_size, void* d_ws, size_t ws_size,
                              hipStream_t stream)
{
    const float* x     = (const float*)d_in[0];
    const int*   mask  = (const int*)d_in[1];
    const float* Wih_f = (const float*)d_in[2];
    const float* Whh_f = (const float*)d_in[3];
    const float* bih_f = (const float*)d_in[4];
    const float* bhh_f = (const float*)d_in[5];
    const float* Wih_r = (const float*)d_in[6];
    const float* Whh_r = (const float*)d_in[7];
    const float* bih_r = (const float*)d_in[8];
    const float* bhh_r = (const float*)d_in[9];
    const float* fc1_w = (const float*)d_in[10];
    const float* fc2_w = (const float*)d_in[11];
    const float* fc3_w = (const float*)d_in[12];
    const float* fc3_b = (const float*)d_in[13];
    const float* Wih_d = (const float*)d_in[14];
    const float* Whh_d = (const float*)d_in[15];
    const float* bih_d = (const float*)d_in[16];
    const float* bhh_d = (const float*)d_in[17];
    const float* lin_w = (const float*)d_in[18];
    const float* lin_b = (const float*)d_in[19];

    float* ws = (float*)d_ws;
    float* Gf   = ws;
    float* Gr   = ws + 8388608;
    float* hs   = ws + 16777216;
    float* wat  = ws + 25165824;
    float* qp   = ws + 33554432;
    float* kp   = ws + 33718272;
    float* Gd   = ws;
    float* yenc = wat;
    ull* hbuf = (ull*)(wat + 4194304);   // 2*NB*256 tagged words
    unsigned short* hsT_hi = (unsigned short*)ws;
    unsigned short* hsT_lo = (unsigned short*)(ws + 2097152);

    float* outp = (float*)d_out;
    const int M = NB * TSEQ;       // 16384
    dim3 blk(256);

    // 1-2. encoder input projections (split-bf16 MFMA, 128x128 tiles)
    gemm_mfma<1><<<dim3(M / 128, 4), blk, 0, stream>>>(x, DB, Wih_f, DB, bih_f, bhh_f, Gf, 512, DB);
    gemm_mfma<2><<<dim3(M / 128, 4), blk, 0, stream>>>(x, DB, Wih_r, DB, bih_r, bhh_r, Gr, 512, DB);
    // 3. bidirectional recurrence
    enc_scan<<<dim3(64), dim3(512), 0, stream>>>(Gf, Gr, Whh_f, Whh_r, hs);
    // 3.5 transpose hs cols 0:256 into bf16 planes (Gf region now dead)
    hs_transpose<<<dim3(8, 4, NB), blk, 0, stream>>>(hs, hsT_hi, hsT_lo);
    // 4-5. q/k projections (tiny N, f32 64x64)
    gemm_nt<0><<<dim3(M / 64, 1), blk, 0, stream>>>(hs, 512, fc1_w, 512, nullptr, nullptr, qp, 10, 10, 256);
    gemm_nt<0><<<dim3(M / 64, 1), blk, 0, stream>>>(hs, 512, fc1_w + 256, 512, nullptr, nullptr, kp, 10, 10, 256);
    // 6. attention scores + softmax
    attn_w<<<dim3(M), blk, 0, stream>>>(qp, kp, mask, fc2_w, wat);
    // 7. ctx = w @ hs (split-bf16 MFMA via transposed planes)
    bgemm_mfma<<<dim3(4, 2, NB), blk, 0, stream>>>(wat, hsT_hi, hsT_lo, hs);
    // 8. y_enc (split-bf16 MFMA)
    gemm_mfma<0><<<dim3(M / 128, 2), blk, 0, stream>>>(hs, 512, fc3_w, 512, fc3_b, nullptr, yenc, 256, 512);
    // 8.5 decoder comm init (pre-split packed words)
    dec_init6<<<dim3(16), blk, 0, stream>>>(hs, hbuf);
    // 9. decoder input projection (split-bf16 MFMA)
    gemm_mfma<1><<<dim3(M / 128, 8), blk, 0, stream>>>(yenc, 256, Wih_d, 272, bih_d, bhh_d, Gd, 1024, 256);
    // 10. decoder recurrence (scan11 sync + register-hoisted weight frags)
    dec_scan14<<<dim3(128), dim3(320), 0, stream>>>(Gd, Whh_d, Wih_d, lin_w, lin_b, hbuf, outp);
}